// Round 1
// baseline (402.389 us; speedup 1.0000x reference)
//
#include <hip/hip_runtime.h>
#include <stdint.h>

#define B_   16
#define N_   4096
#define M_   1024
#define C1_  256
#define C2_  512
#define H_   256
#define K1_  768      // C1+C2
#define P_   65536    // B*N

typedef unsigned int  uint_t;
typedef unsigned short ushort_t;
typedef __attribute__((ext_vector_type(4))) float f32x4;
typedef __attribute__((ext_vector_type(8))) short s16x8;

__device__ __forceinline__ float b2f(ushort_t u) {
    union { uint_t i; float f; } v; v.i = ((uint_t)u) << 16; return v.f;
}
__device__ __forceinline__ ushort_t f2b(float f) {
    union { float f; uint_t i; } v; v.f = f;
    uint_t x = v.i;
    return (ushort_t)((x + 0x7fffu + ((x >> 16) & 1u)) >> 16);  // RNE
}

__device__ __forceinline__ void async16(const void* g, void* l) {
    __builtin_amdgcn_global_load_lds(
        (const __attribute__((address_space(1))) uint_t*)g,
        (__attribute__((address_space(3))) uint_t*)l, 16, 0, 0);
}

// ---------------------------------------------------------------------------
__global__ __launch_bounds__(256) void zero_k(float* __restrict__ p) {
    p[blockIdx.x * 256 + threadIdx.x] = 0.0f;
}

// ---------------------------------------------------------------------------
// Convert w1 (256x768 f32) and w2 (256x256 f32) to bf16.
// ---------------------------------------------------------------------------
__global__ __launch_bounds__(256) void cvtw_k(
    const float* __restrict__ w1, const float* __restrict__ w2,
    ushort_t* __restrict__ w1b, ushort_t* __restrict__ w2b) {
    int t = blockIdx.x * 256 + threadIdx.x;   // 262144 total
    if (t < H_ * K1_) w1b[t] = f2b(w1[t]);
    else { int u = t - H_ * K1_; w2b[u] = f2b(w2[u]); }
}

// ---------------------------------------------------------------------------
// known_feats (B, 512, 1024) f32 -> kfT (B, 1024, 512) bf16, 64x64 LDS tiles
// ---------------------------------------------------------------------------
__global__ __launch_bounds__(256) void tkf_k(
    const float* __restrict__ in, ushort_t* __restrict__ out) {
    __shared__ ushort_t tile[64][65];
    int m0 = blockIdx.x * 64, c0 = blockIdx.y * 64, b = blockIdx.z;
    int t = threadIdx.x;
    {
        int ml = t & 63, cb = (t >> 6) * 16;
        const float* ip = in + ((size_t)b * C2_ + c0) * M_ + m0;
        for (int i = 0; i < 16; ++i)
            tile[cb + i][ml] = f2b(ip[(size_t)(cb + i) * M_ + ml]);
    }
    __syncthreads();
    {
        int cl = t & 63, mb = (t >> 6) * 16;
        for (int i = 0; i < 16; ++i)
            out[((size_t)b * M_ + m0 + mb + i) * C2_ + c0 + cl] = tile[cl][mb + i];
    }
}

// ---------------------------------------------------------------------------
// 3-NN, 8 threads per point.
// NEW: fp32 hot loop tracking top-4 (branchless sorted insert, float compare
// only). Because interp = sum_i w_i f_i is permutation-invariant in the
// selected set, only the 3rd/4th boundary matters. If the fp32 gap
// d4-d3 <= MARGIN (covers fp32 rounding-order differences vs reference,
// ~2e-5 bound, 10x safety) the point's 8 lanes fall back to the EXACT
// previous fp64 path (verbatim -> bit-identical selection + weights).
// Flag rate ~1-2% of points => ~13% of waves pay the fp64 loop once more.
// ---------------------------------------------------------------------------
__device__ __forceinline__ void ins3d(double d, int m,
                                      double& d0, int& i0, double& d1, int& i1,
                                      double& d2, int& i2) {
    if (d < d2 || (d == d2 && m < i2)) {
        d2 = d; i2 = m;
        if (d2 < d1 || (d2 == d1 && i2 < i1)) { double td = d1; d1 = d2; d2 = td; int ti = i1; i1 = i2; i2 = ti; }
        if (d1 < d0 || (d1 == d0 && i1 < i0)) { double td = d0; d0 = d1; d1 = td; int ti = i0; i0 = i1; i1 = ti; }
    }
}

// branchless sorted insert keeping the 4 smallest (strict float compare;
// index tie-break intentionally omitted -- boundary ties are caught by the
// margin check and routed to the fp64 path)
__device__ __forceinline__ void ins4f(float d, int m,
        float& d0, int& i0, float& d1, int& i1,
        float& d2, int& i2, float& d3, int& i3) {
    bool c3 = d < d3;
    float x3 = c3 ? d : d3;   int y3 = c3 ? m : i3;
    bool c2 = x3 < d2;
    float lo2 = c2 ? x3 : d2; int lj2 = c2 ? y3 : i2;
    float hi2 = c2 ? d2 : x3; int hj2 = c2 ? i2 : y3;
    bool c1 = lo2 < d1;
    float lo1 = c1 ? lo2 : d1; int lj1 = c1 ? lj2 : i1;
    float hi1 = c1 ? d1 : lo2; int hj1 = c1 ? i1 : lj2;
    bool c0 = lo1 < d0;
    float nl0 = c0 ? lo1 : d0; int nj0 = c0 ? lj1 : i0;
    float nh0 = c0 ? d0 : lo1; int nk0 = c0 ? i0 : lj1;
    d0 = nl0; i0 = nj0;
    d1 = nh0; i1 = nk0;
    d2 = hi1; i2 = hj1;
    d3 = hi2; i3 = hj2;
}

__global__ __launch_bounds__(256) void knn_k(
    const float* __restrict__ unknown, const float* __restrict__ known,
    int4* __restrict__ idx3, float4* __restrict__ wgt3) {
    __shared__ float4 kpt[M_];             // (x, y, z, |k|^2 fp32) — 16 KB
    int b = blockIdx.x >> 7;               // 2048 blocks, 128 per batch
    int n0 = (blockIdx.x & 127) * 32;      // 32 points per block
    int t = threadIdx.x;
    int pl = t >> 3;                       // point-local 0..31
    int sub = t & 7;                       // candidate slice 0..7

    for (int m = t; m < M_; m += 256) {
        float x = known[((size_t)b * M_ + m) * 3 + 0];
        float y = known[((size_t)b * M_ + m) * 3 + 1];
        float z = known[((size_t)b * M_ + m) * 3 + 2];
        kpt[m] = make_float4(x, y, z, x * x + y * y + z * z);
    }
    __syncthreads();

    int n = n0 + pl;
    float qx = unknown[((size_t)b * N_ + n) * 3 + 0];
    float qy = unknown[((size_t)b * N_ + n) * 3 + 1];
    float qz = unknown[((size_t)b * N_ + n) * 3 + 2];
    float qs = qx * qx + qy * qy + qz * qz;

    const float FMAXV = 3.0e38f;
    float D0[2], D1[2], D2[2], D3[2];
    int   I0[2], I1[2], I2[2], I3[2];
#pragma unroll
    for (int s = 0; s < 2; ++s) {
        D0[s] = FMAXV; D1[s] = FMAXV; D2[s] = FMAXV; D3[s] = FMAXV;
        I0[s] = 0x7fffffff; I1[s] = 0x7fffffff; I2[s] = 0x7fffffff; I3[s] = 0x7fffffff;
    }

    for (int j = 0; j < 64; ++j) {
#pragma unroll
        for (int s = 0; s < 2; ++s) {
            int m = 8 * (2 * j + s) + sub;   // interleaved: distinct banks per sub
            float4 kp = kpt[m];
            float dot = fmaf(qx, kp.x, fmaf(qy, kp.y, qz * kp.z));
            float d = fmaf(-2.0f, dot, qs + kp.w);
            ins4f(d, m, D0[s], I0[s], D1[s], I1[s], D2[s], I2[s], D3[s], I3[s]);
        }
    }
    // merge stream 1 into 0
    ins4f(D0[1], I0[1], D0[0], I0[0], D1[0], I1[0], D2[0], I2[0], D3[0], I3[0]);
    ins4f(D1[1], I1[1], D0[0], I0[0], D1[0], I1[0], D2[0], I2[0], D3[0], I3[0]);
    ins4f(D2[1], I2[1], D0[0], I0[0], D1[0], I1[0], D2[0], I2[0], D3[0], I3[0]);
    ins4f(D3[1], I3[1], D0[0], I0[0], D1[0], I1[0], D2[0], I2[0], D3[0], I3[0]);

    // merge across the 8 subs (lane bits 0..2) — symmetric butterfly
#pragma unroll
    for (int off = 1; off < 8; off <<= 1) {
        float e0 = __shfl_xor(D0[0], off), e1 = __shfl_xor(D1[0], off);
        float e2 = __shfl_xor(D2[0], off), e3 = __shfl_xor(D3[0], off);
        int   j0 = __shfl_xor(I0[0], off), j1 = __shfl_xor(I1[0], off);
        int   j2 = __shfl_xor(I2[0], off), j3 = __shfl_xor(I3[0], off);
        ins4f(e0, j0, D0[0], I0[0], D1[0], I1[0], D2[0], I2[0], D3[0], I3[0]);
        ins4f(e1, j1, D0[0], I0[0], D1[0], I1[0], D2[0], I2[0], D3[0], I3[0]);
        ins4f(e2, j2, D0[0], I0[0], D1[0], I1[0], D2[0], I2[0], D3[0], I3[0]);
        ins4f(e3, j3, D0[0], I0[0], D1[0], I1[0], D2[0], I2[0], D3[0], I3[0]);
    }
    // all 8 lanes of a point now hold identical merged top-4

    // ambiguity check at the 3rd/4th boundary; margin = 10x conservative
    // bound on (kernel + reference) fp32 rounding differences
    bool flagged = (D3[0] - D2[0]) <= 2.0e-4f;

    double E0, E1, E2; int F0, F1, F2;
    if (!flagged) {
        E0 = (double)D0[0]; E1 = (double)D1[0]; E2 = (double)D2[0];
        F0 = I0[0]; F1 = I1[0]; F2 = I2[0];
    } else {
        // exact fp64 path (verbatim from previous kernel -> bit-identical)
        double qdx = (double)qx, qdy = (double)qy, qdz = (double)qz;
        double qds = qdx * qdx + qdy * qdy + qdz * qdz;
        double A0[2], A1[2], A2[2];
        int    B0[2], B1[2], B2[2];
#pragma unroll
        for (int s = 0; s < 2; ++s) {
            A0[s] = 1e300; A1[s] = 1e300; A2[s] = 1e300;
            B0[s] = 0x7fffffff; B1[s] = 0x7fffffff; B2[s] = 0x7fffffff;
        }
        for (int j = 0; j < 64; ++j) {
#pragma unroll
            for (int s = 0; s < 2; ++s) {
                int m = 8 * (2 * j + s) + sub;
                float4 kp = kpt[m];
                double X = (double)kp.x, Y = (double)kp.y, Z = (double)kp.z;
                double ks = X * X + Y * Y + Z * Z;          // same order as before
                double dot = qdx * X + qdy * Y + qdz * Z;
                double dd = qds + ks - 2.0 * dot;
                ins3d(dd, m, A0[s], B0[s], A1[s], B1[s], A2[s], B2[s]);
            }
        }
        ins3d(A0[1], B0[1], A0[0], B0[0], A1[0], B1[0], A2[0], B2[0]);
        ins3d(A1[1], B1[1], A0[0], B0[0], A1[0], B1[0], A2[0], B2[0]);
        ins3d(A2[1], B2[1], A0[0], B0[0], A1[0], B1[0], A2[0], B2[0]);
#pragma unroll
        for (int off = 1; off < 8; off <<= 1) {
            double e0 = __shfl_xor(A0[0], off), e1 = __shfl_xor(A1[0], off), e2 = __shfl_xor(A2[0], off);
            int    j0 = __shfl_xor(B0[0], off), j1 = __shfl_xor(B1[0], off), j2 = __shfl_xor(B2[0], off);
            ins3d(e0, j0, A0[0], B0[0], A1[0], B1[0], A2[0], B2[0]);
            ins3d(e1, j1, A0[0], B0[0], A1[0], B1[0], A2[0], B2[0]);
            ins3d(e2, j2, A0[0], B0[0], A1[0], B1[0], A2[0], B2[0]);
        }
        E0 = A0[0]; E1 = A1[0]; E2 = A2[0];
        F0 = B0[0]; F1 = B1[0]; F2 = B2[0];
    }

    if (sub == 0) {
        double w0 = 1.0 / (E0 + 1e-8);
        double w1 = 1.0 / (E1 + 1e-8);
        double w2 = 1.0 / (E2 + 1e-8);
        double inv = 1.0 / (w0 + w1 + w2);
        size_t p = (size_t)b * N_ + n;
        idx3[p] = make_int4(F0, F1, F2, 0);
        wgt3[p] = make_float4((float)(w0 * inv), (float)(w1 * inv), (float)(w2 * inv), 0.f);
    }
}

// ---------------------------------------------------------------------------
// Weighted gather: wave per point, 8 points/wave, idx/wgt prefetch depth 1.
// interp (P, 512) bf16.
// ---------------------------------------------------------------------------
__global__ __launch_bounds__(256) void gather_k(
    const int4* __restrict__ idx3, const float4* __restrict__ wgt3,
    const ushort_t* __restrict__ kfT, ushort_t* __restrict__ interp) {
    int blk = blockIdx.x;             // 2048 blocks
    int b = blk >> 7;                 // 128 blocks per batch
    int n0 = (blk & 127) * 32;
    int lane = threadIdx.x & 63, wid = threadIdx.x >> 6;

    size_t pbase = (size_t)b * N_ + n0 + wid * 8;
    int4 id = idx3[pbase];
    float4 w = wgt3[pbase];
    for (int it = 0; it < 8; ++it) {
        int4 idn; float4 wn;
        if (it < 7) { idn = idx3[pbase + it + 1]; wn = wgt3[pbase + it + 1]; }
        const uint4* r0 = (const uint4*)(kfT + ((size_t)b * M_ + id.x) * C2_);
        const uint4* r1 = (const uint4*)(kfT + ((size_t)b * M_ + id.y) * C2_);
        const uint4* r2 = (const uint4*)(kfT + ((size_t)b * M_ + id.z) * C2_);
        uint4 v0 = r0[lane], v1 = r1[lane], v2 = r2[lane];
        const ushort_t* p0 = (const ushort_t*)&v0;
        const ushort_t* p1 = (const ushort_t*)&v1;
        const ushort_t* p2 = (const ushort_t*)&v2;
        uint4 o; ushort_t* po = (ushort_t*)&o;
        for (int j = 0; j < 8; ++j) {
            float f = w.x * b2f(p0[j]) + w.y * b2f(p1[j]) + w.z * b2f(p2[j]);
            po[j] = f2b(f);
        }
        ((uint4*)(interp + (pbase + it) * C2_))[lane] = o;
        id = idn; w = wn;
    }
}

// ---------------------------------------------------------------------------
// GEMM1: x1(P,256) = [ufT | interp] (P,768) * w1b(256,768)^T, bf16 MFMA.
// K<256: A staged from uf f32 — each thread packs 8 channels of one row and
//        emits one conflict-free ds_write_b128 (64 B lane stride).
// K>=256: A staged from interp bf16 via global_load_lds (16B).
// ---------------------------------------------------------------------------
__global__ __launch_bounds__(256) void gemm1_k(
    const float* __restrict__ uf, const ushort_t* __restrict__ interp,
    const ushort_t* __restrict__ w1b, ushort_t* __restrict__ x1) {
    __shared__ ushort_t As[128 * 32];
    __shared__ ushort_t Bs[128 * 32];
    int t = threadIdx.x, lane = t & 63, wid = t >> 6;
    int wm = wid & 1, wn = wid >> 1;
    int row0 = blockIdx.x * 128, col0 = blockIdx.y * 128;
    int quad = lane >> 4, l15 = lane & 15;
    int srow = lane >> 2, kc = lane & 3;
    int b = row0 >> 12, nb = row0 & 4095;   // 128 points always within one batch

    f32x4 acc[4][4] = {};

    for (int k0 = 0; k0 < K1_; k0 += 32) {
        if (k0 < C1_) {
            const float* up = uf + ((size_t)b * C1_ + k0) * N_ + nb;
#pragma unroll
            for (int i = 0; i < 2; ++i) {
                int id = i * 256 + t;        // 0..511
                int r = id & 127;            // point row
                int c = id >> 7;             // 8-channel chunk 0..3
                float v[8];
#pragma unroll
                for (int j = 0; j < 8; ++j)
                    v[j] = up[(size_t)(c * 8 + j) * N_ + r];
                uint4 pk;
                pk.x = (uint_t)f2b(v[0]) | ((uint_t)f2b(v[1]) << 16);
                pk.y = (uint_t)f2b(v[2]) | ((uint_t)f2b(v[3]) << 16);
                pk.z = (uint_t)f2b(v[4]) | ((uint_t)f2b(v[5]) << 16);
                pk.w = (uint_t)f2b(v[6]) | ((uint_t)f2b(v[7]) << 16);
                *(uint4*)&As[r * 32 + c * 8] = pk;   // byte addr 64r+16c: conflict-free
            }
        } else {
            for (int j = 0; j < 2; ++j) {
                int rbase = wid * 32 + j * 16;
                async16(interp + ((size_t)(row0 + rbase + srow)) * C2_ + (k0 - C1_) + kc * 8,
                        &As[rbase * 32]);
            }
        }
        for (int j = 0; j < 2; ++j) {
            int rbase = wid * 32 + j * 16;
            async16(w1b + ((size_t)(col0 + rbase + srow)) * K1_ + k0 + kc * 8,
                    &Bs[rbase * 32]);
        }
        __syncthreads();

        s16x8 af[4], bfr[4];
        for (int i = 0; i < 4; ++i)
            af[i] = *(const s16x8*)&As[(wm * 64 + i * 16 + l15) * 32 + quad * 8];
        for (int j = 0; j < 4; ++j)
            bfr[j] = *(const s16x8*)&Bs[(wn * 64 + j * 16 + l15) * 32 + quad * 8];
        for (int i = 0; i < 4; ++i)
            for (int j = 0; j < 4; ++j)
                acc[i][j] = __builtin_amdgcn_mfma_f32_16x16x32_bf16(
                    af[i], bfr[j], acc[i][j], 0, 0, 0);
        __syncthreads();
    }

    for (int i = 0; i < 4; ++i)
        for (int j = 0; j < 4; ++j)
            for (int r = 0; r < 4; ++r) {
                int m = row0 + wm * 64 + i * 16 + quad * 4 + r;
                int n = col0 + wn * 64 + j * 16 + l15;
                x1[(size_t)m * H_ + n] = f2b(acc[i][j][r]);
            }
}

// ---------------------------------------------------------------------------
// GEMM2 (plain): C(P,256) = A(P,K) * Bw(256,K)^T, bf16, K param (=256).
// ---------------------------------------------------------------------------
__global__ __launch_bounds__(256) void gemm_bt_k(
    const ushort_t* __restrict__ A, const ushort_t* __restrict__ Bw,
    ushort_t* __restrict__ C, int K) {
    __shared__ ushort_t As[128 * 32];
    __shared__ ushort_t Bs[128 * 32];
    int t = threadIdx.x, lane = t & 63, wid = t >> 6;
    int wm = wid & 1, wn = wid >> 1;
    int row0 = blockIdx.x * 128, col0 = blockIdx.y * 128;
    int quad = lane >> 4, l15 = lane & 15;
    int srow = lane >> 2, kc = lane & 3;

    f32x4 acc[4][4] = {};

    for (int k0 = 0; k0 < K; k0 += 32) {
        for (int j = 0; j < 2; ++j) {
            int rbase = wid * 32 + j * 16;
            async16(A + ((size_t)(row0 + rbase + srow)) * K + k0 + kc * 8,
                    &As[rbase * 32]);
            async16(Bw + ((size_t)(col0 + rbase + srow)) * K + k0 + kc * 8,
                    &Bs[rbase * 32]);
        }
        __syncthreads();

        s16x8 af[4], bfr[4];
        for (int i = 0; i < 4; ++i)
            af[i] = *(const s16x8*)&As[(wm * 64 + i * 16 + l15) * 32 + quad * 8];
        for (int j = 0; j < 4; ++j)
            bfr[j] = *(const s16x8*)&Bs[(wn * 64 + j * 16 + l15) * 32 + quad * 8];
        for (int i = 0; i < 4; ++i)
            for (int j = 0; j < 4; ++j)
                acc[i][j] = __builtin_amdgcn_mfma_f32_16x16x32_bf16(
                    af[i], bfr[j], acc[i][j], 0, 0, 0);
        __syncthreads();
    }

    for (int i = 0; i < 4; ++i)
        for (int j = 0; j < 4; ++j)
            for (int r = 0; r < 4; ++r) {
                int m = row0 + wm * 64 + i * 16 + quad * 4 + r;
                int n = col0 + wn * 64 + j * 16 + l15;
                C[(size_t)m * H_ + n] = f2b(acc[i][j][r]);
            }
}

// ---------------------------------------------------------------------------
__global__ __launch_bounds__(256) void stats_k(
    const ushort_t* __restrict__ x, float* __restrict__ sum, float* __restrict__ sq) {
    int t = threadIdx.x;
    int r0 = blockIdx.x * 256;
    float s = 0.f, q = 0.f;
    for (int r = 0; r < 256; ++r) {
        float v = b2f(x[(size_t)(r0 + r) * 256 + t]);
        s += v; q += v * v;
    }
    atomicAdd(&sum[t], s);
    atomicAdd(&sq[t], q);
}

__global__ __launch_bounds__(256) void coef_k(
    const float* __restrict__ sum, const float* __restrict__ sq,
    const float* __restrict__ g, const float* __restrict__ bt,
    float* __restrict__ a, float* __restrict__ c) {
    int t = threadIdx.x;
    float mean = sum[t] * (1.0f / P_);
    float var  = sq[t] * (1.0f / P_) - mean * mean;
    float ai = g[t] * rsqrtf(var + 1e-5f);
    a[t] = ai;
    c[t] = bt[t] - mean * ai;
}

// BN + ReLU elementwise: x1 (P,256) bf16 -> h1 bf16, one uint4 (8 elems)/thread
__global__ __launch_bounds__(256) void bnrelu_k(
    const uint4* __restrict__ x, const float* __restrict__ a,
    const float* __restrict__ c, uint4* __restrict__ h) {
    size_t i = (size_t)blockIdx.x * 256 + threadIdx.x;   // 2,097,152 uint4s
    uint4 v = x[i];
    int chb = (int)((i * 8) & 255);
    const ushort_t* pv = (const ushort_t*)&v;
    uint4 o; ushort_t* po = (ushort_t*)&o;
    for (int j = 0; j < 8; ++j) {
        float f = b2f(pv[j]);
        f = a[chb + j] * f + c[chb + j];
        po[j] = f2b(fmaxf(f, 0.0f));
    }
    h[i] = o;
}

// BN + ReLU + transpose: x2 (P,256) bf16 -> out (B,256,N) f32, 64x64 tiles
__global__ __launch_bounds__(256) void final_k(
    const ushort_t* __restrict__ x2, const float* __restrict__ a,
    const float* __restrict__ c, float* __restrict__ out) {
    __shared__ float tile[64][65];
    int n0 = blockIdx.x * 64, c0 = blockIdx.y * 64, b = blockIdx.z;
    int t = threadIdx.x;
    {
        int cl = t & 63, pb = (t >> 6) * 16;
        float av = a[c0 + cl], cv = c[c0 + cl];
        for (int i = 0; i < 16; ++i) {
            float v = b2f(x2[((size_t)b * N_ + n0 + pb + i) * H_ + c0 + cl]);
            tile[cl][pb + i] = fmaxf(av * v + cv, 0.0f);
        }
    }
    __syncthreads();
    {
        int nl = t & 63, cb = (t >> 6) * 16;
        for (int i = 0; i < 16; ++i)
            out[((size_t)b * H_ + c0 + cb + i) * N_ + n0 + nl] = tile[cb + i][nl];
    }
}

// ---------------------------------------------------------------------------
extern "C" void kernel_launch(void* const* d_in, const int* in_sizes, int n_in,
                              void* d_out, int out_size, void* d_ws, size_t ws_size,
                              hipStream_t stream) {
    const float* unknown = (const float*)d_in[0];
    const float* known   = (const float*)d_in[1];
    const float* uf      = (const float*)d_in[2];
    const float* kf      = (const float*)d_in[3];
    const float* w1      = (const float*)d_in[4];
    const float* g1      = (const float*)d_in[5];
    const float* b1      = (const float*)d_in[6];
    const float* w2      = (const float*)d_in[7];
    const float* g2      = (const float*)d_in[8];
    const float* b2      = (const float*)d_in[9];
    float* out = (float*)d_out;

    char* ws = (char*)d_ws;
    // [0, 8K): stats — sum1,sq1,sum2,sq2,a1,c1,a2,c2 (8 x 256 f32)
    float* sum1 = (float*)ws;
    float* sq1  = sum1 + 256;
    float* sum2 = sum1 + 512;
    float* sq2  = sum1 + 768;
    float* a1   = sum1 + 1024;
    float* c1   = sum1 + 1280;
    float* a2   = sum1 + 1536;
    float* c2   = sum1 + 1792;
    // [8K, ~520K): converted weights
    ushort_t* w1b = (ushort_t*)(ws + 8192);                        // 384 KB
    ushort_t* w2b = (ushort_t*)(ws + 8192 + (size_t)H_ * K1_ * 2); // 128 KB
    const size_t MB = 1024 * 1024;
    ushort_t* kfT    = (ushort_t*)(ws + 1 * MB);    // 16 MB  [dead after gather_k]
    ushort_t* interp = (ushort_t*)(ws + 17 * MB);   // 64 MB  [dead after gemm1]
    ushort_t* h1     = (ushort_t*)(ws + 17 * MB);   // 32 MB  (over interp lo half)
    ushort_t* x2     = (ushort_t*)(ws + 49 * MB);   // 32 MB  (over interp hi half)
    ushort_t* x1     = (ushort_t*)(ws + 81 * MB);   // 32 MB
    // knn outputs live in the (not-yet-written) x1 region; consumed by gather_k
    // strictly before gemm1 writes x1 (same stream, serialized).
    int4*   idx3 = (int4*)(ws + 81 * MB);           // 1 MB
    float4* wgt3 = (float4*)(ws + 82 * MB);         // 1 MB  -> peak 113 MB

    zero_k<<<8, 256, 0, stream>>>(sum1);
    cvtw_k<<<1024, 256, 0, stream>>>(w1, w2, w1b, w2b);
    tkf_k<<<dim3(16, 8, 16), 256, 0, stream>>>(kf, kfT);
    knn_k<<<2048, 256, 0, stream>>>(unknown, known, idx3, wgt3);
    gather_k<<<2048, 256, 0, stream>>>(idx3, wgt3, kfT, interp);
    gemm1_k<<<dim3(512, 2), 256, 0, stream>>>(uf, interp, w1b, x1);
    stats_k<<<256, 256, 0, stream>>>(x1, sum1, sq1);
    coef_k<<<1, 256, 0, stream>>>(sum1, sq1, g1, b1, a1, c1);
    bnrelu_k<<<8192, 256, 0, stream>>>((const uint4*)x1, a1, c1, (uint4*)h1);
    gemm_bt_k<<<dim3(512, 2), 256, 0, stream>>>(h1, w2b, x2, H_);
    stats_k<<<256, 256, 0, stream>>>(x2, sum2, sq2);
    coef_k<<<1, 256, 0, stream>>>(sum2, sq2, g2, b2, a2, c2);
    final_k<<<dim3(64, 4, 16), 256, 0, stream>>>(x2, a2, c2, out);
}

// Round 2
// 377.744 us; speedup vs baseline: 1.0652x; 1.0652x over previous
//
#include <hip/hip_runtime.h>
#include <stdint.h>

#define B_   16
#define N_   4096
#define M_   1024
#define C1_  256
#define C2_  512
#define H_   256
#define K1_  768      // C1+C2
#define P_   65536    // B*N

typedef unsigned int  uint_t;
typedef unsigned short ushort_t;
typedef __attribute__((ext_vector_type(4))) float f32x4;
typedef __attribute__((ext_vector_type(8))) short s16x8;

__device__ __forceinline__ float b2f(ushort_t u) {
    union { uint_t i; float f; } v; v.i = ((uint_t)u) << 16; return v.f;
}
__device__ __forceinline__ ushort_t f2b(float f) {
    union { float f; uint_t i; } v; v.f = f;
    uint_t x = v.i;
    return (ushort_t)((x + 0x7fffu + ((x >> 16) & 1u)) >> 16);  // RNE
}

__device__ __forceinline__ void async16(const void* g, void* l) {
    __builtin_amdgcn_global_load_lds(
        (const __attribute__((address_space(1))) uint_t*)g,
        (__attribute__((address_space(3))) uint_t*)l, 16, 0, 0);
}

// ---------------------------------------------------------------------------
__global__ __launch_bounds__(256) void zero_k(float* __restrict__ p) {
    p[blockIdx.x * 256 + threadIdx.x] = 0.0f;
}

// ---------------------------------------------------------------------------
// Convert w1 (256x768 f32) and w2 (256x256 f32) to bf16.
// ---------------------------------------------------------------------------
__global__ __launch_bounds__(256) void cvtw_k(
    const float* __restrict__ w1, const float* __restrict__ w2,
    ushort_t* __restrict__ w1b, ushort_t* __restrict__ w2b) {
    int t = blockIdx.x * 256 + threadIdx.x;   // 262144 total
    if (t < H_ * K1_) w1b[t] = f2b(w1[t]);
    else { int u = t - H_ * K1_; w2b[u] = f2b(w2[u]); }
}

// ---------------------------------------------------------------------------
// known_feats (B, 512, 1024) f32 -> kfT (B, 1024, 512) bf16, 64x64 LDS tiles
// ---------------------------------------------------------------------------
__global__ __launch_bounds__(256) void tkf_k(
    const float* __restrict__ in, ushort_t* __restrict__ out) {
    __shared__ ushort_t tile[64][65];
    int m0 = blockIdx.x * 64, c0 = blockIdx.y * 64, b = blockIdx.z;
    int t = threadIdx.x;
    {
        int ml = t & 63, cb = (t >> 6) * 16;
        const float* ip = in + ((size_t)b * C2_ + c0) * M_ + m0;
        for (int i = 0; i < 16; ++i)
            tile[cb + i][ml] = f2b(ip[(size_t)(cb + i) * M_ + ml]);
    }
    __syncthreads();
    {
        int cl = t & 63, mb = (t >> 6) * 16;
        for (int i = 0; i < 16; ++i)
            out[((size_t)b * M_ + m0 + mb + i) * C2_ + c0 + cl] = tile[cl][mb + i];
    }
}

// ---------------------------------------------------------------------------
// 3-NN, 8 threads per point.
// fp32 hot loop keeps sorted top-3 (d,i) + value-only 4th distance:
//   3 PARALLEL compares + 11 cndmask + 1 min per candidate (short dep chain).
// Gap check: if (d4 - d3) <= MARGIN (6e-5; ~3x the worst-case fp32 eval
// divergence vs the fp32 JAX reference / fp64 truth at these magnitudes),
// the point's lanes take a CHEAP exact fallback: fp32 rescan + fp64
// lexicographic insert only for candidates with d_f32 <= D2f + 6e-5
// (provable superset of the true top-3). Lexicographic (d,m) top-3 is
// insertion-order independent -> identical to a full fp64 pass.
// ---------------------------------------------------------------------------
__device__ __forceinline__ void ins3d(double d, int m,
                                      double& d0, int& i0, double& d1, int& i1,
                                      double& d2, int& i2) {
    if (d < d2 || (d == d2 && m < i2)) {
        d2 = d; i2 = m;
        if (d2 < d1 || (d2 == d1 && i2 < i1)) { double td = d1; d1 = d2; d2 = td; int ti = i1; i1 = i2; i2 = ti; }
        if (d1 < d0 || (d1 == d0 && i1 < i0)) { double td = d0; d0 = d1; d1 = td; int ti = i0; i0 = i1; i1 = ti; }
    }
}

// sorted insert of (d,m) into top-3 (d0..d2,i0..i2) + value-only d3.
// compares are mutually independent (c0 => c1 => c2 by sortedness).
__device__ __forceinline__ void ins4(float d, int m,
        float& d0, int& i0, float& d1, int& i1,
        float& d2, int& i2, float& d3) {
    bool c2 = d < d2, c1 = d < d1, c0 = d < d0;
    float t3 = fminf(d3, d);
    d3 = c2 ? d2 : t3;
    float e2 = c1 ? d1 : d;  int f2c = c1 ? i1 : m;
    d2 = c2 ? e2 : d2;       i2 = c2 ? f2c : i2;
    float e1 = c0 ? d0 : d;  int f1c = c0 ? i0 : m;
    d1 = c1 ? e1 : d1;       i1 = c1 ? f1c : i1;
    d0 = c0 ? d : d0;        i0 = c0 ? m : i0;
}

__global__ __launch_bounds__(256) void knn_k(
    const float* __restrict__ unknown, const float* __restrict__ known,
    int4* __restrict__ idx3, float4* __restrict__ wgt3) {
    __shared__ float4 kpt[M_];             // (x, y, z, |k|^2 fp32) — 16 KB
    int b = blockIdx.x >> 7;               // 2048 blocks, 128 per batch
    int n0 = (blockIdx.x & 127) * 32;      // 32 points per block
    int t = threadIdx.x;
    int pl = t >> 3;                       // point-local 0..31
    int sub = t & 7;                       // candidate slice 0..7

    for (int m = t; m < M_; m += 256) {
        float x = known[((size_t)b * M_ + m) * 3 + 0];
        float y = known[((size_t)b * M_ + m) * 3 + 1];
        float z = known[((size_t)b * M_ + m) * 3 + 2];
        kpt[m] = make_float4(x, y, z, x * x + y * y + z * z);
    }
    __syncthreads();

    int n = n0 + pl;
    float qx = unknown[((size_t)b * N_ + n) * 3 + 0];
    float qy = unknown[((size_t)b * N_ + n) * 3 + 1];
    float qz = unknown[((size_t)b * N_ + n) * 3 + 2];
    float qs = qx * qx + qy * qy + qz * qz;

    const float FMAXV = 3.0e38f;
    const float MARGIN = 6.0e-5f;
    float D0[2], D1[2], D2[2], D3[2];
    int   I0[2], I1[2], I2[2];
#pragma unroll
    for (int s = 0; s < 2; ++s) {
        D0[s] = FMAXV; D1[s] = FMAXV; D2[s] = FMAXV; D3[s] = FMAXV;
        I0[s] = 0x7fffffff; I1[s] = 0x7fffffff; I2[s] = 0x7fffffff;
    }

#pragma unroll 4
    for (int j = 0; j < 64; ++j) {
#pragma unroll
        for (int s = 0; s < 2; ++s) {
            int m = 8 * (2 * j + s) + sub;   // interleaved: distinct banks per sub
            float4 kp = kpt[m];
            float dot = fmaf(qx, kp.x, fmaf(qy, kp.y, qz * kp.z));
            float d = fmaf(-2.0f, dot, qs + kp.w);
            ins4(d, m, D0[s], I0[s], D1[s], I1[s], D2[s], I2[s], D3[s]);
        }
    }
    // merge stream 1 into 0 (insert its top-3 pairs, then min the 4th value)
    ins4(D0[1], I0[1], D0[0], I0[0], D1[0], I1[0], D2[0], I2[0], D3[0]);
    ins4(D1[1], I1[1], D0[0], I0[0], D1[0], I1[0], D2[0], I2[0], D3[0]);
    ins4(D2[1], I2[1], D0[0], I0[0], D1[0], I1[0], D2[0], I2[0], D3[0]);
    D3[0] = fminf(D3[0], D3[1]);

    // merge across the 8 subs (lane bits 0..2) — symmetric butterfly
#pragma unroll
    for (int off = 1; off < 8; off <<= 1) {
        float e0 = __shfl_xor(D0[0], off), e1 = __shfl_xor(D1[0], off);
        float e2 = __shfl_xor(D2[0], off), e3 = __shfl_xor(D3[0], off);
        int   j0 = __shfl_xor(I0[0], off), j1 = __shfl_xor(I1[0], off);
        int   j2 = __shfl_xor(I2[0], off);
        ins4(e0, j0, D0[0], I0[0], D1[0], I1[0], D2[0], I2[0], D3[0]);
        ins4(e1, j1, D0[0], I0[0], D1[0], I1[0], D2[0], I2[0], D3[0]);
        ins4(e2, j2, D0[0], I0[0], D1[0], I1[0], D2[0], I2[0], D3[0]);
        D3[0] = fminf(D3[0], e3);
    }
    // all 8 lanes of a point now hold the same top-3 set and 4th distance

    // ambiguity check at the 3rd/4th boundary
    bool flagged = (D3[0] - D2[0]) <= MARGIN;

    double E0, E1, E2; int F0, F1, F2;
    if (!flagged) {
        E0 = (double)D0[0]; E1 = (double)D1[0]; E2 = (double)D2[0];
        F0 = I0[0]; F1 = I1[0]; F2 = I2[0];
    } else {
        // exact fallback: fp32 rescan + fp64 lexicographic insert for the
        // few candidates that can possibly be in the true top-3.
        float fthr = D2[0] + MARGIN;
        double qdx = (double)qx, qdy = (double)qy, qdz = (double)qz;
        double qds = qdx * qdx + qdy * qdy + qdz * qdz;
        double A0 = 1e300, A1 = 1e300, A2 = 1e300;
        int    G0 = 0x7fffffff, G1 = 0x7fffffff, G2 = 0x7fffffff;
        for (int m = sub; m < M_; m += 8) {
            float4 kp = kpt[m];
            float dot = fmaf(qx, kp.x, fmaf(qy, kp.y, qz * kp.z));
            float df = fmaf(-2.0f, dot, qs + kp.w);
            if (df <= fthr) {
                double X = (double)kp.x, Y = (double)kp.y, Z = (double)kp.z;
                double ks = X * X + Y * Y + Z * Z;          // same order as fp64 ref
                double dd = qdx * X + qdy * Y + qdz * Z;
                double de = qds + ks - 2.0 * dd;
                ins3d(de, m, A0, G0, A1, G1, A2, G2);
            }
        }
#pragma unroll
        for (int off = 1; off < 8; off <<= 1) {
            double e0 = __shfl_xor(A0, off), e1 = __shfl_xor(A1, off), e2 = __shfl_xor(A2, off);
            int    j0 = __shfl_xor(G0, off), j1 = __shfl_xor(G1, off), j2 = __shfl_xor(G2, off);
            ins3d(e0, j0, A0, G0, A1, G1, A2, G2);
            ins3d(e1, j1, A0, G0, A1, G1, A2, G2);
            ins3d(e2, j2, A0, G0, A1, G1, A2, G2);
        }
        E0 = A0; E1 = A1; E2 = A2;
        F0 = G0; F1 = G1; F2 = G2;
    }

    if (sub == 0) {
        double w0 = 1.0 / (E0 + 1e-8);
        double w1 = 1.0 / (E1 + 1e-8);
        double w2 = 1.0 / (E2 + 1e-8);
        double inv = 1.0 / (w0 + w1 + w2);
        size_t p = (size_t)b * N_ + n;
        idx3[p] = make_int4(F0, F1, F2, 0);
        wgt3[p] = make_float4((float)(w0 * inv), (float)(w1 * inv), (float)(w2 * inv), 0.f);
    }
}

// ---------------------------------------------------------------------------
// Weighted gather: wave per point, 8 points/wave, idx/wgt prefetch depth 1.
// interp (P, 512) bf16.
// ---------------------------------------------------------------------------
__global__ __launch_bounds__(256) void gather_k(
    const int4* __restrict__ idx3, const float4* __restrict__ wgt3,
    const ushort_t* __restrict__ kfT, ushort_t* __restrict__ interp) {
    int blk = blockIdx.x;             // 2048 blocks
    int b = blk >> 7;                 // 128 blocks per batch
    int n0 = (blk & 127) * 32;
    int lane = threadIdx.x & 63, wid = threadIdx.x >> 6;

    size_t pbase = (size_t)b * N_ + n0 + wid * 8;
    int4 id = idx3[pbase];
    float4 w = wgt3[pbase];
    for (int it = 0; it < 8; ++it) {
        int4 idn; float4 wn;
        if (it < 7) { idn = idx3[pbase + it + 1]; wn = wgt3[pbase + it + 1]; }
        const uint4* r0 = (const uint4*)(kfT + ((size_t)b * M_ + id.x) * C2_);
        const uint4* r1 = (const uint4*)(kfT + ((size_t)b * M_ + id.y) * C2_);
        const uint4* r2 = (const uint4*)(kfT + ((size_t)b * M_ + id.z) * C2_);
        uint4 v0 = r0[lane], v1 = r1[lane], v2 = r2[lane];
        const ushort_t* p0 = (const ushort_t*)&v0;
        const ushort_t* p1 = (const ushort_t*)&v1;
        const ushort_t* p2 = (const ushort_t*)&v2;
        uint4 o; ushort_t* po = (ushort_t*)&o;
        for (int j = 0; j < 8; ++j) {
            float f = w.x * b2f(p0[j]) + w.y * b2f(p1[j]) + w.z * b2f(p2[j]);
            po[j] = f2b(f);
        }
        ((uint4*)(interp + (pbase + it) * C2_))[lane] = o;
        id = idn; w = wn;
    }
}

// ---------------------------------------------------------------------------
// GEMM1: x1(P,256) = [ufT | interp] (P,768) * w1b(256,768)^T, bf16 MFMA.
// K<256: A staged from uf f32 — each thread packs 8 channels of one row and
//        emits one conflict-free ds_write_b128 (64 B lane stride).
// K>=256: A staged from interp bf16 via global_load_lds (16B).
// ---------------------------------------------------------------------------
__global__ __launch_bounds__(256) void gemm1_k(
    const float* __restrict__ uf, const ushort_t* __restrict__ interp,
    const ushort_t* __restrict__ w1b, ushort_t* __restrict__ x1) {
    __shared__ ushort_t As[128 * 32];
    __shared__ ushort_t Bs[128 * 32];
    int t = threadIdx.x, lane = t & 63, wid = t >> 6;
    int wm = wid & 1, wn = wid >> 1;
    int row0 = blockIdx.x * 128, col0 = blockIdx.y * 128;
    int quad = lane >> 4, l15 = lane & 15;
    int srow = lane >> 2, kc = lane & 3;
    int b = row0 >> 12, nb = row0 & 4095;   // 128 points always within one batch

    f32x4 acc[4][4] = {};

    for (int k0 = 0; k0 < K1_; k0 += 32) {
        if (k0 < C1_) {
            const float* up = uf + ((size_t)b * C1_ + k0) * N_ + nb;
#pragma unroll
            for (int i = 0; i < 2; ++i) {
                int id = i * 256 + t;        // 0..511
                int r = id & 127;            // point row
                int c = id >> 7;             // 8-channel chunk 0..3
                float v[8];
#pragma unroll
                for (int j = 0; j < 8; ++j)
                    v[j] = up[(size_t)(c * 8 + j) * N_ + r];
                uint4 pk;
                pk.x = (uint_t)f2b(v[0]) | ((uint_t)f2b(v[1]) << 16);
                pk.y = (uint_t)f2b(v[2]) | ((uint_t)f2b(v[3]) << 16);
                pk.z = (uint_t)f2b(v[4]) | ((uint_t)f2b(v[5]) << 16);
                pk.w = (uint_t)f2b(v[6]) | ((uint_t)f2b(v[7]) << 16);
                *(uint4*)&As[r * 32 + c * 8] = pk;   // byte addr 64r+16c: conflict-free
            }
        } else {
            for (int j = 0; j < 2; ++j) {
                int rbase = wid * 32 + j * 16;
                async16(interp + ((size_t)(row0 + rbase + srow)) * C2_ + (k0 - C1_) + kc * 8,
                        &As[rbase * 32]);
            }
        }
        for (int j = 0; j < 2; ++j) {
            int rbase = wid * 32 + j * 16;
            async16(w1b + ((size_t)(col0 + rbase + srow)) * K1_ + k0 + kc * 8,
                    &Bs[rbase * 32]);
        }
        __syncthreads();

        s16x8 af[4], bfr[4];
        for (int i = 0; i < 4; ++i)
            af[i] = *(const s16x8*)&As[(wm * 64 + i * 16 + l15) * 32 + quad * 8];
        for (int j = 0; j < 4; ++j)
            bfr[j] = *(const s16x8*)&Bs[(wn * 64 + j * 16 + l15) * 32 + quad * 8];
        for (int i = 0; i < 4; ++i)
            for (int j = 0; j < 4; ++j)
                acc[i][j] = __builtin_amdgcn_mfma_f32_16x16x32_bf16(
                    af[i], bfr[j], acc[i][j], 0, 0, 0);
        __syncthreads();
    }

    for (int i = 0; i < 4; ++i)
        for (int j = 0; j < 4; ++j)
            for (int r = 0; r < 4; ++r) {
                int m = row0 + wm * 64 + i * 16 + quad * 4 + r;
                int n = col0 + wn * 64 + j * 16 + l15;
                x1[(size_t)m * H_ + n] = f2b(acc[i][j][r]);
            }
}

// ---------------------------------------------------------------------------
// GEMM2 (plain): C(P,256) = A(P,K) * Bw(256,K)^T, bf16, K param (=256).
// ---------------------------------------------------------------------------
__global__ __launch_bounds__(256) void gemm_bt_k(
    const ushort_t* __restrict__ A, const ushort_t* __restrict__ Bw,
    ushort_t* __restrict__ C, int K) {
    __shared__ ushort_t As[128 * 32];
    __shared__ ushort_t Bs[128 * 32];
    int t = threadIdx.x, lane = t & 63, wid = t >> 6;
    int wm = wid & 1, wn = wid >> 1;
    int row0 = blockIdx.x * 128, col0 = blockIdx.y * 128;
    int quad = lane >> 4, l15 = lane & 15;
    int srow = lane >> 2, kc = lane & 3;

    f32x4 acc[4][4] = {};

    for (int k0 = 0; k0 < K; k0 += 32) {
        for (int j = 0; j < 2; ++j) {
            int rbase = wid * 32 + j * 16;
            async16(A + ((size_t)(row0 + rbase + srow)) * K + k0 + kc * 8,
                    &As[rbase * 32]);
            async16(Bw + ((size_t)(col0 + rbase + srow)) * K + k0 + kc * 8,
                    &Bs[rbase * 32]);
        }
        __syncthreads();

        s16x8 af[4], bfr[4];
        for (int i = 0; i < 4; ++i)
            af[i] = *(const s16x8*)&As[(wm * 64 + i * 16 + l15) * 32 + quad * 8];
        for (int j = 0; j < 4; ++j)
            bfr[j] = *(const s16x8*)&Bs[(wn * 64 + j * 16 + l15) * 32 + quad * 8];
        for (int i = 0; i < 4; ++i)
            for (int j = 0; j < 4; ++j)
                acc[i][j] = __builtin_amdgcn_mfma_f32_16x16x32_bf16(
                    af[i], bfr[j], acc[i][j], 0, 0, 0);
        __syncthreads();
    }

    for (int i = 0; i < 4; ++i)
        for (int j = 0; j < 4; ++j)
            for (int r = 0; r < 4; ++r) {
                int m = row0 + wm * 64 + i * 16 + quad * 4 + r;
                int n = col0 + wn * 64 + j * 16 + l15;
                C[(size_t)m * H_ + n] = f2b(acc[i][j][r]);
            }
}

// ---------------------------------------------------------------------------
__global__ __launch_bounds__(256) void stats_k(
    const ushort_t* __restrict__ x, float* __restrict__ sum, float* __restrict__ sq) {
    int t = threadIdx.x;
    int r0 = blockIdx.x * 256;
    float s = 0.f, q = 0.f;
    for (int r = 0; r < 256; ++r) {
        float v = b2f(x[(size_t)(r0 + r) * 256 + t]);
        s += v; q += v * v;
    }
    atomicAdd(&sum[t], s);
    atomicAdd(&sq[t], q);
}

__global__ __launch_bounds__(256) void coef_k(
    const float* __restrict__ sum, const float* __restrict__ sq,
    const float* __restrict__ g, const float* __restrict__ bt,
    float* __restrict__ a, float* __restrict__ c) {
    int t = threadIdx.x;
    float mean = sum[t] * (1.0f / P_);
    float var  = sq[t] * (1.0f / P_) - mean * mean;
    float ai = g[t] * rsqrtf(var + 1e-5f);
    a[t] = ai;
    c[t] = bt[t] - mean * ai;
}

// BN + ReLU elementwise: x1 (P,256) bf16 -> h1 bf16, one uint4 (8 elems)/thread
__global__ __launch_bounds__(256) void bnrelu_k(
    const uint4* __restrict__ x, const float* __restrict__ a,
    const float* __restrict__ c, uint4* __restrict__ h) {
    size_t i = (size_t)blockIdx.x * 256 + threadIdx.x;   // 2,097,152 uint4s
    uint4 v = x[i];
    int chb = (int)((i * 8) & 255);
    const ushort_t* pv = (const ushort_t*)&v;
    uint4 o; ushort_t* po = (ushort_t*)&o;
    for (int j = 0; j < 8; ++j) {
        float f = b2f(pv[j]);
        f = a[chb + j] * f + c[chb + j];
        po[j] = f2b(fmaxf(f, 0.0f));
    }
    h[i] = o;
}

// BN + ReLU + transpose: x2 (P,256) bf16 -> out (B,256,N) f32, 64x64 tiles
__global__ __launch_bounds__(256) void final_k(
    const ushort_t* __restrict__ x2, const float* __restrict__ a,
    const float* __restrict__ c, float* __restrict__ out) {
    __shared__ float tile[64][65];
    int n0 = blockIdx.x * 64, c0 = blockIdx.y * 64, b = blockIdx.z;
    int t = threadIdx.x;
    {
        int cl = t & 63, pb = (t >> 6) * 16;
        float av = a[c0 + cl], cv = c[c0 + cl];
        for (int i = 0; i < 16; ++i) {
            float v = b2f(x2[((size_t)b * N_ + n0 + pb + i) * H_ + c0 + cl]);
            tile[cl][pb + i] = fmaxf(av * v + cv, 0.0f);
        }
    }
    __syncthreads();
    {
        int nl = t & 63, cb = (t >> 6) * 16;
        for (int i = 0; i < 16; ++i)
            out[((size_t)b * H_ + c0 + cb + i) * N_ + n0 + nl] = tile[cb + i][nl];
    }
}

// ---------------------------------------------------------------------------
extern "C" void kernel_launch(void* const* d_in, const int* in_sizes, int n_in,
                              void* d_out, int out_size, void* d_ws, size_t ws_size,
                              hipStream_t stream) {
    const float* unknown = (const float*)d_in[0];
    const float* known   = (const float*)d_in[1];
    const float* uf      = (const float*)d_in[2];
    const float* kf      = (const float*)d_in[3];
    const float* w1      = (const float*)d_in[4];
    const float* g1      = (const float*)d_in[5];
    const float* b1      = (const float*)d_in[6];
    const float* w2      = (const float*)d_in[7];
    const float* g2      = (const float*)d_in[8];
    const float* b2      = (const float*)d_in[9];
    float* out = (float*)d_out;

    char* ws = (char*)d_ws;
    // [0, 8K): stats — sum1,sq1,sum2,sq2,a1,c1,a2,c2 (8 x 256 f32)
    float* sum1 = (float*)ws;
    float* sq1  = sum1 + 256;
    float* sum2 = sum1 + 512;
    float* sq2  = sum1 + 768;
    float* a1   = sum1 + 1024;
    float* c1   = sum1 + 1280;
    float* a2   = sum1 + 1536;
    float* c2   = sum1 + 1792;
    // [8K, ~520K): converted weights
    ushort_t* w1b = (ushort_t*)(ws + 8192);                        // 384 KB
    ushort_t* w2b = (ushort_t*)(ws + 8192 + (size_t)H_ * K1_ * 2); // 128 KB
    const size_t MB = 1024 * 1024;
    ushort_t* kfT    = (ushort_t*)(ws + 1 * MB);    // 16 MB  [dead after gather_k]
    ushort_t* interp = (ushort_t*)(ws + 17 * MB);   // 64 MB  [dead after gemm1]
    ushort_t* h1     = (ushort_t*)(ws + 17 * MB);   // 32 MB  (over interp lo half)
    ushort_t* x2     = (ushort_t*)(ws + 49 * MB);   // 32 MB  (over interp hi half)
    ushort_t* x1     = (ushort_t*)(ws + 81 * MB);   // 32 MB
    // knn outputs live in the (not-yet-written) x1 region; consumed by gather_k
    // strictly before gemm1 writes x1 (same stream, serialized).
    int4*   idx3 = (int4*)(ws + 81 * MB);           // 1 MB
    float4* wgt3 = (float4*)(ws + 82 * MB);         // 1 MB  -> peak 113 MB

    zero_k<<<8, 256, 0, stream>>>(sum1);
    cvtw_k<<<1024, 256, 0, stream>>>(w1, w2, w1b, w2b);
    tkf_k<<<dim3(16, 8, 16), 256, 0, stream>>>(kf, kfT);
    knn_k<<<2048, 256, 0, stream>>>(unknown, known, idx3, wgt3);
    gather_k<<<2048, 256, 0, stream>>>(idx3, wgt3, kfT, interp);
    gemm1_k<<<dim3(512, 2), 256, 0, stream>>>(uf, interp, w1b, x1);
    stats_k<<<256, 256, 0, stream>>>(x1, sum1, sq1);
    coef_k<<<1, 256, 0, stream>>>(sum1, sq1, g1, b1, a1, c1);
    bnrelu_k<<<8192, 256, 0, stream>>>((const uint4*)x1, a1, c1, (uint4*)h1);
    gemm_bt_k<<<dim3(512, 2), 256, 0, stream>>>(h1, w2b, x2, H_);
    stats_k<<<256, 256, 0, stream>>>(x2, sum2, sq2);
    coef_k<<<1, 256, 0, stream>>>(sum2, sq2, g2, b2, a2, c2);
    final_k<<<dim3(64, 4, 16), 256, 0, stream>>>(x2, a2, c2, out);
}

// Round 3
// 373.876 us; speedup vs baseline: 1.0763x; 1.0103x over previous
//
#include <hip/hip_runtime.h>
#include <stdint.h>

#define B_   16
#define N_   4096
#define M_   1024
#define C1_  256
#define C2_  512
#define H_   256
#define K1_  768      // C1+C2
#define P_   65536    // B*N

typedef unsigned int  uint_t;
typedef unsigned short ushort_t;
typedef __attribute__((ext_vector_type(4))) float f32x4;
typedef __attribute__((ext_vector_type(8))) short s16x8;

__device__ __forceinline__ float b2f(ushort_t u) {
    union { uint_t i; float f; } v; v.i = ((uint_t)u) << 16; return v.f;
}
__device__ __forceinline__ ushort_t f2b(float f) {
    union { float f; uint_t i; } v; v.f = f;
    uint_t x = v.i;
    return (ushort_t)((x + 0x7fffu + ((x >> 16) & 1u)) >> 16);  // RNE
}

__device__ __forceinline__ void async16(const void* g, void* l) {
    __builtin_amdgcn_global_load_lds(
        (const __attribute__((address_space(1))) uint_t*)g,
        (__attribute__((address_space(3))) uint_t*)l, 16, 0, 0);
}

// ---------------------------------------------------------------------------
__global__ __launch_bounds__(256) void zero_k(float* __restrict__ p) {
    p[blockIdx.x * 256 + threadIdx.x] = 0.0f;
}

// ---------------------------------------------------------------------------
// Convert w1 (256x768 f32) and w2 (256x256 f32) to bf16.
// ---------------------------------------------------------------------------
__global__ __launch_bounds__(256) void cvtw_k(
    const float* __restrict__ w1, const float* __restrict__ w2,
    ushort_t* __restrict__ w1b, ushort_t* __restrict__ w2b) {
    int t = blockIdx.x * 256 + threadIdx.x;   // 262144 total
    if (t < H_ * K1_) w1b[t] = f2b(w1[t]);
    else { int u = t - H_ * K1_; w2b[u] = f2b(w2[u]); }
}

// ---------------------------------------------------------------------------
// known_feats (B, 512, 1024) f32 -> kfT (B, 1024, 512) bf16, 64x64 LDS tiles
// ---------------------------------------------------------------------------
__global__ __launch_bounds__(256) void tkf_k(
    const float* __restrict__ in, ushort_t* __restrict__ out) {
    __shared__ ushort_t tile[64][65];
    int m0 = blockIdx.x * 64, c0 = blockIdx.y * 64, b = blockIdx.z;
    int t = threadIdx.x;
    {
        int ml = t & 63, cb = (t >> 6) * 16;
        const float* ip = in + ((size_t)b * C2_ + c0) * M_ + m0;
        for (int i = 0; i < 16; ++i)
            tile[cb + i][ml] = f2b(ip[(size_t)(cb + i) * M_ + ml]);
    }
    __syncthreads();
    {
        int cl = t & 63, mb = (t >> 6) * 16;
        for (int i = 0; i < 16; ++i)
            out[((size_t)b * M_ + m0 + mb + i) * C2_ + c0 + cl] = tile[cl][mb + i];
    }
}

// ---------------------------------------------------------------------------
// 3-NN, 8 threads per point. fp32 hot loop (top-3 + 4th value), exact
// filtered fp64 fallback when the 3rd/4th boundary is ambiguous.
// ---------------------------------------------------------------------------
__device__ __forceinline__ void ins3d(double d, int m,
                                      double& d0, int& i0, double& d1, int& i1,
                                      double& d2, int& i2) {
    if (d < d2 || (d == d2 && m < i2)) {
        d2 = d; i2 = m;
        if (d2 < d1 || (d2 == d1 && i2 < i1)) { double td = d1; d1 = d2; d2 = td; int ti = i1; i1 = i2; i2 = ti; }
        if (d1 < d0 || (d1 == d0 && i1 < i0)) { double td = d0; d0 = d1; d1 = td; int ti = i0; i0 = i1; i1 = ti; }
    }
}

__device__ __forceinline__ void ins4(float d, int m,
        float& d0, int& i0, float& d1, int& i1,
        float& d2, int& i2, float& d3) {
    bool c2 = d < d2, c1 = d < d1, c0 = d < d0;
    float t3 = fminf(d3, d);
    d3 = c2 ? d2 : t3;
    float e2 = c1 ? d1 : d;  int f2c = c1 ? i1 : m;
    d2 = c2 ? e2 : d2;       i2 = c2 ? f2c : i2;
    float e1 = c0 ? d0 : d;  int f1c = c0 ? i0 : m;
    d1 = c1 ? e1 : d1;       i1 = c1 ? f1c : i1;
    d0 = c0 ? d : d0;        i0 = c0 ? m : i0;
}

__global__ __launch_bounds__(256) void knn_k(
    const float* __restrict__ unknown, const float* __restrict__ known,
    int4* __restrict__ idx3, float4* __restrict__ wgt3) {
    __shared__ float4 kpt[M_];             // (x, y, z, |k|^2 fp32) — 16 KB
    int b = blockIdx.x >> 7;               // 2048 blocks, 128 per batch
    int n0 = (blockIdx.x & 127) * 32;      // 32 points per block
    int t = threadIdx.x;
    int pl = t >> 3;                       // point-local 0..31
    int sub = t & 7;                       // candidate slice 0..7

    for (int m = t; m < M_; m += 256) {
        float x = known[((size_t)b * M_ + m) * 3 + 0];
        float y = known[((size_t)b * M_ + m) * 3 + 1];
        float z = known[((size_t)b * M_ + m) * 3 + 2];
        kpt[m] = make_float4(x, y, z, x * x + y * y + z * z);
    }
    __syncthreads();

    int n = n0 + pl;
    float qx = unknown[((size_t)b * N_ + n) * 3 + 0];
    float qy = unknown[((size_t)b * N_ + n) * 3 + 1];
    float qz = unknown[((size_t)b * N_ + n) * 3 + 2];
    float qs = qx * qx + qy * qy + qz * qz;

    const float FMAXV = 3.0e38f;
    const float MARGIN = 6.0e-5f;
    float D0[2], D1[2], D2[2], D3[2];
    int   I0[2], I1[2], I2[2];
#pragma unroll
    for (int s = 0; s < 2; ++s) {
        D0[s] = FMAXV; D1[s] = FMAXV; D2[s] = FMAXV; D3[s] = FMAXV;
        I0[s] = 0x7fffffff; I1[s] = 0x7fffffff; I2[s] = 0x7fffffff;
    }

#pragma unroll 4
    for (int j = 0; j < 64; ++j) {
#pragma unroll
        for (int s = 0; s < 2; ++s) {
            int m = 8 * (2 * j + s) + sub;   // interleaved: distinct banks per sub
            float4 kp = kpt[m];
            float dot = fmaf(qx, kp.x, fmaf(qy, kp.y, qz * kp.z));
            float d = fmaf(-2.0f, dot, qs + kp.w);
            ins4(d, m, D0[s], I0[s], D1[s], I1[s], D2[s], I2[s], D3[s]);
        }
    }
    // merge stream 1 into 0 (insert its top-3 pairs, then min the 4th value)
    ins4(D0[1], I0[1], D0[0], I0[0], D1[0], I1[0], D2[0], I2[0], D3[0]);
    ins4(D1[1], I1[1], D0[0], I0[0], D1[0], I1[0], D2[0], I2[0], D3[0]);
    ins4(D2[1], I2[1], D0[0], I0[0], D1[0], I1[0], D2[0], I2[0], D3[0]);
    D3[0] = fminf(D3[0], D3[1]);

    // merge across the 8 subs (lane bits 0..2) — symmetric butterfly
#pragma unroll
    for (int off = 1; off < 8; off <<= 1) {
        float e0 = __shfl_xor(D0[0], off), e1 = __shfl_xor(D1[0], off);
        float e2 = __shfl_xor(D2[0], off), e3 = __shfl_xor(D3[0], off);
        int   j0 = __shfl_xor(I0[0], off), j1 = __shfl_xor(I1[0], off);
        int   j2 = __shfl_xor(I2[0], off);
        ins4(e0, j0, D0[0], I0[0], D1[0], I1[0], D2[0], I2[0], D3[0]);
        ins4(e1, j1, D0[0], I0[0], D1[0], I1[0], D2[0], I2[0], D3[0]);
        ins4(e2, j2, D0[0], I0[0], D1[0], I1[0], D2[0], I2[0], D3[0]);
        D3[0] = fminf(D3[0], e3);
    }
    // all 8 lanes of a point now hold the same top-3 set and 4th distance

    // ambiguity check at the 3rd/4th boundary
    bool flagged = (D3[0] - D2[0]) <= MARGIN;

    double E0, E1, E2; int F0, F1, F2;
    if (!flagged) {
        E0 = (double)D0[0]; E1 = (double)D1[0]; E2 = (double)D2[0];
        F0 = I0[0]; F1 = I1[0]; F2 = I2[0];
    } else {
        // exact fallback: fp32 rescan + fp64 lexicographic insert for the
        // few candidates that can possibly be in the true top-3.
        float fthr = D2[0] + MARGIN;
        double qdx = (double)qx, qdy = (double)qy, qdz = (double)qz;
        double qds = qdx * qdx + qdy * qdy + qdz * qdz;
        double A0 = 1e300, A1 = 1e300, A2 = 1e300;
        int    G0 = 0x7fffffff, G1 = 0x7fffffff, G2 = 0x7fffffff;
        for (int m = sub; m < M_; m += 8) {
            float4 kp = kpt[m];
            float dot = fmaf(qx, kp.x, fmaf(qy, kp.y, qz * kp.z));
            float df = fmaf(-2.0f, dot, qs + kp.w);
            if (df <= fthr) {
                double X = (double)kp.x, Y = (double)kp.y, Z = (double)kp.z;
                double ks = X * X + Y * Y + Z * Z;          // same order as fp64 ref
                double dd = qdx * X + qdy * Y + qdz * Z;
                double de = qds + ks - 2.0 * dd;
                ins3d(de, m, A0, G0, A1, G1, A2, G2);
            }
        }
#pragma unroll
        for (int off = 1; off < 8; off <<= 1) {
            double e0 = __shfl_xor(A0, off), e1 = __shfl_xor(A1, off), e2 = __shfl_xor(A2, off);
            int    j0 = __shfl_xor(G0, off), j1 = __shfl_xor(G1, off), j2 = __shfl_xor(G2, off);
            ins3d(e0, j0, A0, G0, A1, G1, A2, G2);
            ins3d(e1, j1, A0, G0, A1, G1, A2, G2);
            ins3d(e2, j2, A0, G0, A1, G1, A2, G2);
        }
        E0 = A0; E1 = A1; E2 = A2;
        F0 = G0; F1 = G1; F2 = G2;
    }

    if (sub == 0) {
        double w0 = 1.0 / (E0 + 1e-8);
        double w1 = 1.0 / (E1 + 1e-8);
        double w2 = 1.0 / (E2 + 1e-8);
        double inv = 1.0 / (w0 + w1 + w2);
        size_t p = (size_t)b * N_ + n;
        idx3[p] = make_int4(F0, F1, F2, 0);
        wgt3[p] = make_float4((float)(w0 * inv), (float)(w1 * inv), (float)(w2 * inv), 0.f);
    }
}

// ---------------------------------------------------------------------------
// Weighted gather: wave per point, 8 points/wave, idx/wgt prefetch depth 1.
// interp (P, 512) bf16.
// ---------------------------------------------------------------------------
__global__ __launch_bounds__(256) void gather_k(
    const int4* __restrict__ idx3, const float4* __restrict__ wgt3,
    const ushort_t* __restrict__ kfT, ushort_t* __restrict__ interp) {
    int blk = blockIdx.x;             // 2048 blocks
    int b = blk >> 7;                 // 128 blocks per batch
    int n0 = (blk & 127) * 32;
    int lane = threadIdx.x & 63, wid = threadIdx.x >> 6;

    size_t pbase = (size_t)b * N_ + n0 + wid * 8;
    int4 id = idx3[pbase];
    float4 w = wgt3[pbase];
    for (int it = 0; it < 8; ++it) {
        int4 idn; float4 wn;
        if (it < 7) { idn = idx3[pbase + it + 1]; wn = wgt3[pbase + it + 1]; }
        const uint4* r0 = (const uint4*)(kfT + ((size_t)b * M_ + id.x) * C2_);
        const uint4* r1 = (const uint4*)(kfT + ((size_t)b * M_ + id.y) * C2_);
        const uint4* r2 = (const uint4*)(kfT + ((size_t)b * M_ + id.z) * C2_);
        uint4 v0 = r0[lane], v1 = r1[lane], v2 = r2[lane];
        const ushort_t* p0 = (const ushort_t*)&v0;
        const ushort_t* p1 = (const ushort_t*)&v1;
        const ushort_t* p2 = (const ushort_t*)&v2;
        uint4 o; ushort_t* po = (ushort_t*)&o;
        for (int j = 0; j < 8; ++j) {
            float f = w.x * b2f(p0[j]) + w.y * b2f(p1[j]) + w.z * b2f(p2[j]);
            po[j] = f2b(f);
        }
        ((uint4*)(interp + (pbase + it) * C2_))[lane] = o;
        id = idn; w = wn;
    }
}

// ---------------------------------------------------------------------------
// GEMM1: x1(P,256) = [ufT | interp] (P,768) * w1b(256,768)^T, bf16 MFMA.
// 2-phase double-buffered pipeline (stage t+1 before compute t, ONE barrier
// per K-step). LDS rows are 64B: XOR-swizzle slot = chunk ^ ((row>>1)&3)
// applied at the per-lane GLOBAL source address (LDS dest of global_load_lds
// stays linear) and matched on the ds_read side — spreads the 64B-stride
// reads across all 32 banks (residual 2-way = free).
// K<256: A staged from uf f32 (T14 split: global loads issued before the
//        MFMAs, pack + swizzled ds_write_b128 after them).
// K>=256: A staged from interp bf16 via global_load_lds (16B).
// ---------------------------------------------------------------------------
__global__ __launch_bounds__(256, 4) void gemm1_k(
    const float* __restrict__ uf, const ushort_t* __restrict__ interp,
    const ushort_t* __restrict__ w1b, ushort_t* __restrict__ x1) {
    __shared__ ushort_t As[2][128 * 32];
    __shared__ ushort_t Bs[2][128 * 32];
    int t = threadIdx.x, lane = t & 63, wid = t >> 6;
    int wm = wid & 1, wn = wid >> 1;
    int row0 = blockIdx.x * 128, col0 = blockIdx.y * 128;
    int quad = lane >> 4, l15 = lane & 15;
    int srow = lane >> 2, kc = lane & 3;
    int kcs = kc ^ ((srow >> 1) & 3);       // swizzled source chunk
    int rsw = (l15 >> 1) & 3;               // read-side swizzle key
    int b = row0 >> 12, nb = row0 & 4095;   // 128 points always within one batch

    f32x4 acc[4][4] = {};
    float v[2][8];

    auto stageB = [&](int buf, int k0) {
#pragma unroll
        for (int j = 0; j < 2; ++j) {
            int rbase = wid * 32 + j * 16;
            async16(w1b + ((size_t)(col0 + rbase + srow)) * K1_ + k0 + kcs * 8,
                    &Bs[buf][rbase * 32]);
        }
    };
    auto stageA_hi = [&](int buf, int k0) {
#pragma unroll
        for (int j = 0; j < 2; ++j) {
            int rbase = wid * 32 + j * 16;
            async16(interp + ((size_t)(row0 + rbase + srow)) * C2_ + (k0 - C1_) + kcs * 8,
                    &As[buf][rbase * 32]);
        }
    };
    auto loadA_lo = [&](int k0) {
        const float* up = uf + ((size_t)b * C1_ + k0) * N_ + nb;
#pragma unroll
        for (int i = 0; i < 2; ++i) {
            int id = i * 256 + t;
            int r = id & 127, c = id >> 7;
#pragma unroll
            for (int j = 0; j < 8; ++j)
                v[i][j] = up[(size_t)(c * 8 + j) * N_ + r];
        }
    };
    auto writeA_lo = [&](int buf) {
#pragma unroll
        for (int i = 0; i < 2; ++i) {
            int id = i * 256 + t;
            int r = id & 127, c = id >> 7;
            uint4 pk;
            pk.x = (uint_t)f2b(v[i][0]) | ((uint_t)f2b(v[i][1]) << 16);
            pk.y = (uint_t)f2b(v[i][2]) | ((uint_t)f2b(v[i][3]) << 16);
            pk.z = (uint_t)f2b(v[i][4]) | ((uint_t)f2b(v[i][5]) << 16);
            pk.w = (uint_t)f2b(v[i][6]) | ((uint_t)f2b(v[i][7]) << 16);
            *(uint4*)&As[buf][r * 32 + ((c ^ ((r >> 1) & 3)) * 8)] = pk;
        }
    };

    // prologue: stage tile 0
    loadA_lo(0);
    stageB(0, 0);
    writeA_lo(0);
    __syncthreads();

    int cur = 0;
    for (int it = 0; it < 24; ++it) {
        int kn = it * 32 + 32;
        bool hn = it < 23;
        bool nlo = hn && (kn < C1_);
        if (hn) {
            if (nlo) loadA_lo(kn);
            else     stageA_hi(cur ^ 1, kn);
            stageB(cur ^ 1, kn);
        }

        s16x8 af[4], bfr[4];
#pragma unroll
        for (int i = 0; i < 4; ++i)
            af[i] = *(const s16x8*)&As[cur][(wm * 64 + i * 16 + l15) * 32 + ((quad ^ rsw) * 8)];
#pragma unroll
        for (int j = 0; j < 4; ++j)
            bfr[j] = *(const s16x8*)&Bs[cur][(wn * 64 + j * 16 + l15) * 32 + ((quad ^ rsw) * 8)];
#pragma unroll
        for (int i = 0; i < 4; ++i)
#pragma unroll
            for (int j = 0; j < 4; ++j)
                acc[i][j] = __builtin_amdgcn_mfma_f32_16x16x32_bf16(
                    af[i], bfr[j], acc[i][j], 0, 0, 0);

        if (nlo) writeA_lo(cur ^ 1);
        __syncthreads();
        cur ^= 1;
    }

    for (int i = 0; i < 4; ++i)
        for (int j = 0; j < 4; ++j)
            for (int r = 0; r < 4; ++r) {
                int m = row0 + wm * 64 + i * 16 + quad * 4 + r;
                int n = col0 + wn * 64 + j * 16 + l15;
                x1[(size_t)m * H_ + n] = f2b(acc[i][j][r]);
            }
}

// ---------------------------------------------------------------------------
// GEMM2: C(P,256) = A(P,K) * Bw(256,K)^T, bf16, K param (=256).
// Same 2-phase pipeline + swizzle as gemm1_k, pure global_load_lds staging.
// ---------------------------------------------------------------------------
__global__ __launch_bounds__(256, 4) void gemm_bt_k(
    const ushort_t* __restrict__ A, const ushort_t* __restrict__ Bw,
    ushort_t* __restrict__ C, int K) {
    __shared__ ushort_t As[2][128 * 32];
    __shared__ ushort_t Bs[2][128 * 32];
    int t = threadIdx.x, lane = t & 63, wid = t >> 6;
    int wm = wid & 1, wn = wid >> 1;
    int row0 = blockIdx.x * 128, col0 = blockIdx.y * 128;
    int quad = lane >> 4, l15 = lane & 15;
    int srow = lane >> 2, kc = lane & 3;
    int kcs = kc ^ ((srow >> 1) & 3);
    int rsw = (l15 >> 1) & 3;

    f32x4 acc[4][4] = {};

    auto stage = [&](int buf, int k0) {
#pragma unroll
        for (int j = 0; j < 2; ++j) {
            int rbase = wid * 32 + j * 16;
            async16(A + ((size_t)(row0 + rbase + srow)) * K + k0 + kcs * 8,
                    &As[buf][rbase * 32]);
            async16(Bw + ((size_t)(col0 + rbase + srow)) * K + k0 + kcs * 8,
                    &Bs[buf][rbase * 32]);
        }
    };

    stage(0, 0);
    __syncthreads();

    int cur = 0;
    int nt = K >> 5;
    for (int it = 0; it < nt; ++it) {
        if (it < nt - 1) stage(cur ^ 1, it * 32 + 32);

        s16x8 af[4], bfr[4];
#pragma unroll
        for (int i = 0; i < 4; ++i)
            af[i] = *(const s16x8*)&As[cur][(wm * 64 + i * 16 + l15) * 32 + ((quad ^ rsw) * 8)];
#pragma unroll
        for (int j = 0; j < 4; ++j)
            bfr[j] = *(const s16x8*)&Bs[cur][(wn * 64 + j * 16 + l15) * 32 + ((quad ^ rsw) * 8)];
#pragma unroll
        for (int i = 0; i < 4; ++i)
#pragma unroll
            for (int j = 0; j < 4; ++j)
                acc[i][j] = __builtin_amdgcn_mfma_f32_16x16x32_bf16(
                    af[i], bfr[j], acc[i][j], 0, 0, 0);

        __syncthreads();
        cur ^= 1;
    }

    for (int i = 0; i < 4; ++i)
        for (int j = 0; j < 4; ++j)
            for (int r = 0; r < 4; ++r) {
                int m = row0 + wm * 64 + i * 16 + quad * 4 + r;
                int n = col0 + wn * 64 + j * 16 + l15;
                C[(size_t)m * H_ + n] = f2b(acc[i][j][r]);
            }
}

// ---------------------------------------------------------------------------
__global__ __launch_bounds__(256) void stats_k(
    const ushort_t* __restrict__ x, float* __restrict__ sum, float* __restrict__ sq) {
    int t = threadIdx.x;
    int r0 = blockIdx.x * 256;
    float s = 0.f, q = 0.f;
    for (int r = 0; r < 256; ++r) {
        float v = b2f(x[(size_t)(r0 + r) * 256 + t]);
        s += v; q += v * v;
    }
    atomicAdd(&sum[t], s);
    atomicAdd(&sq[t], q);
}

__global__ __launch_bounds__(256) void coef_k(
    const float* __restrict__ sum, const float* __restrict__ sq,
    const float* __restrict__ g, const float* __restrict__ bt,
    float* __restrict__ a, float* __restrict__ c) {
    int t = threadIdx.x;
    float mean = sum[t] * (1.0f / P_);
    float var  = sq[t] * (1.0f / P_) - mean * mean;
    float ai = g[t] * rsqrtf(var + 1e-5f);
    a[t] = ai;
    c[t] = bt[t] - mean * ai;
}

// BN + ReLU elementwise: x1 (P,256) bf16 -> h1 bf16, one uint4 (8 elems)/thread
__global__ __launch_bounds__(256) void bnrelu_k(
    const uint4* __restrict__ x, const float* __restrict__ a,
    const float* __restrict__ c, uint4* __restrict__ h) {
    size_t i = (size_t)blockIdx.x * 256 + threadIdx.x;   // 2,097,152 uint4s
    uint4 v = x[i];
    int chb = (int)((i * 8) & 255);
    const ushort_t* pv = (const ushort_t*)&v;
    uint4 o; ushort_t* po = (ushort_t*)&o;
    for (int j = 0; j < 8; ++j) {
        float f = b2f(pv[j]);
        f = a[chb + j] * f + c[chb + j];
        po[j] = f2b(fmaxf(f, 0.0f));
    }
    h[i] = o;
}

// BN + ReLU + transpose: x2 (P,256) bf16 -> out (B,256,N) f32, 64x64 tiles
__global__ __launch_bounds__(256) void final_k(
    const ushort_t* __restrict__ x2, const float* __restrict__ a,
    const float* __restrict__ c, float* __restrict__ out) {
    __shared__ float tile[64][65];
    int n0 = blockIdx.x * 64, c0 = blockIdx.y * 64, b = blockIdx.z;
    int t = threadIdx.x;
    {
        int cl = t & 63, pb = (t >> 6) * 16;
        float av = a[c0 + cl], cv = c[c0 + cl];
        for (int i = 0; i < 16; ++i) {
            float v = b2f(x2[((size_t)b * N_ + n0 + pb + i) * H_ + c0 + cl]);
            tile[cl][pb + i] = fmaxf(av * v + cv, 0.0f);
        }
    }
    __syncthreads();
    {
        int nl = t & 63, cb = (t >> 6) * 16;
        for (int i = 0; i < 16; ++i)
            out[((size_t)b * H_ + c0 + cb + i) * N_ + n0 + nl] = tile[cb + i][nl];
    }
}

// ---------------------------------------------------------------------------
extern "C" void kernel_launch(void* const* d_in, const int* in_sizes, int n_in,
                              void* d_out, int out_size, void* d_ws, size_t ws_size,
                              hipStream_t stream) {
    const float* unknown = (const float*)d_in[0];
    const float* known   = (const float*)d_in[1];
    const float* uf      = (const float*)d_in[2];
    const float* kf      = (const float*)d_in[3];
    const float* w1      = (const float*)d_in[4];
    const float* g1      = (const float*)d_in[5];
    const float* b1      = (const float*)d_in[6];
    const float* w2      = (const float*)d_in[7];
    const float* g2      = (const float*)d_in[8];
    const float* b2      = (const float*)d_in[9];
    float* out = (float*)d_out;

    char* ws = (char*)d_ws;
    // [0, 8K): stats — sum1,sq1,sum2,sq2,a1,c1,a2,c2 (8 x 256 f32)
    float* sum1 = (float*)ws;
    float* sq1  = sum1 + 256;
    float* sum2 = sum1 + 512;
    float* sq2  = sum1 + 768;
    float* a1   = sum1 + 1024;
    float* c1   = sum1 + 1280;
    float* a2   = sum1 + 1536;
    float* c2   = sum1 + 1792;
    // [8K, ~520K): converted weights
    ushort_t* w1b = (ushort_t*)(ws + 8192);                        // 384 KB
    ushort_t* w2b = (ushort_t*)(ws + 8192 + (size_t)H_ * K1_ * 2); // 128 KB
    const size_t MB = 1024 * 1024;
    ushort_t* kfT    = (ushort_t*)(ws + 1 * MB);    // 16 MB  [dead after gather_k]
    ushort_t* interp = (ushort_t*)(ws + 17 * MB);   // 64 MB  [dead after gemm1]
    ushort_t* h1     = (ushort_t*)(ws + 17 * MB);   // 32 MB  (over interp lo half)
    ushort_t* x2     = (ushort_t*)(ws + 49 * MB);   // 32 MB  (over interp hi half)
    ushort_t* x1     = (ushort_t*)(ws + 81 * MB);   // 32 MB
    // knn outputs live in the (not-yet-written) x1 region; consumed by gather_k
    // strictly before gemm1 writes x1 (same stream, serialized).
    int4*   idx3 = (int4*)(ws + 81 * MB);           // 1 MB
    float4* wgt3 = (float4*)(ws + 82 * MB);         // 1 MB  -> peak 113 MB

    zero_k<<<8, 256, 0, stream>>>(sum1);
    cvtw_k<<<1024, 256, 0, stream>>>(w1, w2, w1b, w2b);
    tkf_k<<<dim3(16, 8, 16), 256, 0, stream>>>(kf, kfT);
    knn_k<<<2048, 256, 0, stream>>>(unknown, known, idx3, wgt3);
    gather_k<<<2048, 256, 0, stream>>>(idx3, wgt3, kfT, interp);
    gemm1_k<<<dim3(512, 2), 256, 0, stream>>>(uf, interp, w1b, x1);
    stats_k<<<256, 256, 0, stream>>>(x1, sum1, sq1);
    coef_k<<<1, 256, 0, stream>>>(sum1, sq1, g1, b1, a1, c1);
    bnrelu_k<<<8192, 256, 0, stream>>>((const uint4*)x1, a1, c1, (uint4*)h1);
    gemm_bt_k<<<dim3(512, 2), 256, 0, stream>>>(h1, w2b, x2, H_);
    stats_k<<<256, 256, 0, stream>>>(x2, sum2, sq2);
    coef_k<<<1, 256, 0, stream>>>(sum2, sq2, g2, b2, a2, c2);
    final_k<<<dim3(64, 4, 16), 256, 0, stream>>>(x2, a2, c2, out);
}

// Round 4
// 369.323 us; speedup vs baseline: 1.0895x; 1.0123x over previous
//
#include <hip/hip_runtime.h>
#include <stdint.h>

#define B_   16
#define N_   4096
#define M_   1024
#define C1_  256
#define C2_  512
#define H_   256
#define K1_  768      // C1+C2
#define P_   65536    // B*N

typedef unsigned int  uint_t;
typedef unsigned short ushort_t;
typedef __attribute__((ext_vector_type(4))) float f32x4;
typedef __attribute__((ext_vector_type(8))) short s16x8;

__device__ __forceinline__ float b2f(ushort_t u) {
    union { uint_t i; float f; } v; v.i = ((uint_t)u) << 16; return v.f;
}
__device__ __forceinline__ ushort_t f2b(float f) {
    union { float f; uint_t i; } v; v.f = f;
    uint_t x = v.i;
    return (ushort_t)((x + 0x7fffu + ((x >> 16) & 1u)) >> 16);  // RNE
}

__device__ __forceinline__ void async16(const void* g, void* l) {
    __builtin_amdgcn_global_load_lds(
        (const __attribute__((address_space(1))) uint_t*)g,
        (__attribute__((address_space(3))) uint_t*)l, 16, 0, 0);
}

// ---------------------------------------------------------------------------
__global__ __launch_bounds__(256) void zero_k(float* __restrict__ p) {
    p[blockIdx.x * 256 + threadIdx.x] = 0.0f;
}

// ---------------------------------------------------------------------------
// Convert w1 (256x768 f32) and w2 (256x256 f32) to bf16.
// ---------------------------------------------------------------------------
__global__ __launch_bounds__(256) void cvtw_k(
    const float* __restrict__ w1, const float* __restrict__ w2,
    ushort_t* __restrict__ w1b, ushort_t* __restrict__ w2b) {
    int t = blockIdx.x * 256 + threadIdx.x;   // 262144 total
    if (t < H_ * K1_) w1b[t] = f2b(w1[t]);
    else { int u = t - H_ * K1_; w2b[u] = f2b(w2[u]); }
}

// ---------------------------------------------------------------------------
// known_feats (B, 512, 1024) f32 -> kfT (B, 1024, 512) bf16, 64x64 LDS tiles
// ---------------------------------------------------------------------------
__global__ __launch_bounds__(256) void tkf_k(
    const float* __restrict__ in, ushort_t* __restrict__ out) {
    __shared__ ushort_t tile[64][65];
    int m0 = blockIdx.x * 64, c0 = blockIdx.y * 64, b = blockIdx.z;
    int t = threadIdx.x;
    {
        int ml = t & 63, cb = (t >> 6) * 16;
        const float* ip = in + ((size_t)b * C2_ + c0) * M_ + m0;
        for (int i = 0; i < 16; ++i)
            tile[cb + i][ml] = f2b(ip[(size_t)(cb + i) * M_ + ml]);
    }
    __syncthreads();
    {
        int cl = t & 63, mb = (t >> 6) * 16;
        for (int i = 0; i < 16; ++i)
            out[((size_t)b * M_ + m0 + mb + i) * C2_ + c0 + cl] = tile[cl][mb + i];
    }
}

// ---------------------------------------------------------------------------
// uf (B, 256, 4096) f32 -> A_cat (P, 768) bf16 columns 0..255, 64x64 tiles.
// Same f2b RNE as the old in-GEMM pack -> bit-identical A values.
// ---------------------------------------------------------------------------
__global__ __launch_bounds__(256) void tuf_k(
    const float* __restrict__ in, ushort_t* __restrict__ out) {
    __shared__ ushort_t tile[64][65];
    int n0 = blockIdx.x * 64, c0 = blockIdx.y * 64, b = blockIdx.z;
    int t = threadIdx.x;
    {
        int nl = t & 63, cb = (t >> 6) * 16;
        const float* ip = in + ((size_t)b * C1_ + c0) * N_ + n0;
        for (int i = 0; i < 16; ++i)
            tile[cb + i][nl] = f2b(ip[(size_t)(cb + i) * N_ + nl]);
    }
    __syncthreads();
    {
        int cl = t & 63, pb = (t >> 6) * 16;
        for (int i = 0; i < 16; ++i)
            out[((size_t)b * N_ + n0 + pb + i) * K1_ + c0 + cl] = tile[cl][pb + i];
    }
}

// ---------------------------------------------------------------------------
// 3-NN, 8 threads per point. fp32 hot loop (top-3 + 4th value), exact
// filtered fp64 fallback when the 3rd/4th boundary is ambiguous.
// ---------------------------------------------------------------------------
__device__ __forceinline__ void ins3d(double d, int m,
                                      double& d0, int& i0, double& d1, int& i1,
                                      double& d2, int& i2) {
    if (d < d2 || (d == d2 && m < i2)) {
        d2 = d; i2 = m;
        if (d2 < d1 || (d2 == d1 && i2 < i1)) { double td = d1; d1 = d2; d2 = td; int ti = i1; i1 = i2; i2 = ti; }
        if (d1 < d0 || (d1 == d0 && i1 < i0)) { double td = d0; d0 = d1; d1 = td; int ti = i0; i0 = i1; i1 = ti; }
    }
}

__device__ __forceinline__ void ins4(float d, int m,
        float& d0, int& i0, float& d1, int& i1,
        float& d2, int& i2, float& d3) {
    bool c2 = d < d2, c1 = d < d1, c0 = d < d0;
    float t3 = fminf(d3, d);
    d3 = c2 ? d2 : t3;
    float e2 = c1 ? d1 : d;  int f2c = c1 ? i1 : m;
    d2 = c2 ? e2 : d2;       i2 = c2 ? f2c : i2;
    float e1 = c0 ? d0 : d;  int f1c = c0 ? i0 : m;
    d1 = c1 ? e1 : d1;       i1 = c1 ? f1c : i1;
    d0 = c0 ? d : d0;        i0 = c0 ? m : i0;
}

__global__ __launch_bounds__(256) void knn_k(
    const float* __restrict__ unknown, const float* __restrict__ known,
    int4* __restrict__ idx3, float4* __restrict__ wgt3) {
    __shared__ float4 kpt[M_];             // (x, y, z, |k|^2 fp32) — 16 KB
    int b = blockIdx.x >> 7;               // 2048 blocks, 128 per batch
    int n0 = (blockIdx.x & 127) * 32;      // 32 points per block
    int t = threadIdx.x;
    int pl = t >> 3;                       // point-local 0..31
    int sub = t & 7;                       // candidate slice 0..7

    for (int m = t; m < M_; m += 256) {
        float x = known[((size_t)b * M_ + m) * 3 + 0];
        float y = known[((size_t)b * M_ + m) * 3 + 1];
        float z = known[((size_t)b * M_ + m) * 3 + 2];
        kpt[m] = make_float4(x, y, z, x * x + y * y + z * z);
    }
    __syncthreads();

    int n = n0 + pl;
    float qx = unknown[((size_t)b * N_ + n) * 3 + 0];
    float qy = unknown[((size_t)b * N_ + n) * 3 + 1];
    float qz = unknown[((size_t)b * N_ + n) * 3 + 2];
    float qs = qx * qx + qy * qy + qz * qz;

    const float FMAXV = 3.0e38f;
    const float MARGIN = 6.0e-5f;
    float D0[2], D1[2], D2[2], D3[2];
    int   I0[2], I1[2], I2[2];
#pragma unroll
    for (int s = 0; s < 2; ++s) {
        D0[s] = FMAXV; D1[s] = FMAXV; D2[s] = FMAXV; D3[s] = FMAXV;
        I0[s] = 0x7fffffff; I1[s] = 0x7fffffff; I2[s] = 0x7fffffff;
    }

#pragma unroll 4
    for (int j = 0; j < 64; ++j) {
#pragma unroll
        for (int s = 0; s < 2; ++s) {
            int m = 8 * (2 * j + s) + sub;   // interleaved: distinct banks per sub
            float4 kp = kpt[m];
            float dot = fmaf(qx, kp.x, fmaf(qy, kp.y, qz * kp.z));
            float d = fmaf(-2.0f, dot, qs + kp.w);
            ins4(d, m, D0[s], I0[s], D1[s], I1[s], D2[s], I2[s], D3[s]);
        }
    }
    // merge stream 1 into 0 (insert its top-3 pairs, then min the 4th value)
    ins4(D0[1], I0[1], D0[0], I0[0], D1[0], I1[0], D2[0], I2[0], D3[0]);
    ins4(D1[1], I1[1], D0[0], I0[0], D1[0], I1[0], D2[0], I2[0], D3[0]);
    ins4(D2[1], I2[1], D0[0], I0[0], D1[0], I1[0], D2[0], I2[0], D3[0]);
    D3[0] = fminf(D3[0], D3[1]);

    // merge across the 8 subs (lane bits 0..2) — symmetric butterfly
#pragma unroll
    for (int off = 1; off < 8; off <<= 1) {
        float e0 = __shfl_xor(D0[0], off), e1 = __shfl_xor(D1[0], off);
        float e2 = __shfl_xor(D2[0], off), e3 = __shfl_xor(D3[0], off);
        int   j0 = __shfl_xor(I0[0], off), j1 = __shfl_xor(I1[0], off);
        int   j2 = __shfl_xor(I2[0], off);
        ins4(e0, j0, D0[0], I0[0], D1[0], I1[0], D2[0], I2[0], D3[0]);
        ins4(e1, j1, D0[0], I0[0], D1[0], I1[0], D2[0], I2[0], D3[0]);
        ins4(e2, j2, D0[0], I0[0], D1[0], I1[0], D2[0], I2[0], D3[0]);
        D3[0] = fminf(D3[0], e3);
    }
    // all 8 lanes of a point now hold the same top-3 set and 4th distance

    // ambiguity check at the 3rd/4th boundary
    bool flagged = (D3[0] - D2[0]) <= MARGIN;

    double E0, E1, E2; int F0, F1, F2;
    if (!flagged) {
        E0 = (double)D0[0]; E1 = (double)D1[0]; E2 = (double)D2[0];
        F0 = I0[0]; F1 = I1[0]; F2 = I2[0];
    } else {
        // exact fallback: fp32 rescan + fp64 lexicographic insert for the
        // few candidates that can possibly be in the true top-3.
        float fthr = D2[0] + MARGIN;
        double qdx = (double)qx, qdy = (double)qy, qdz = (double)qz;
        double qds = qdx * qdx + qdy * qdy + qdz * qdz;
        double A0 = 1e300, A1 = 1e300, A2 = 1e300;
        int    G0 = 0x7fffffff, G1 = 0x7fffffff, G2 = 0x7fffffff;
        for (int m = sub; m < M_; m += 8) {
            float4 kp = kpt[m];
            float dot = fmaf(qx, kp.x, fmaf(qy, kp.y, qz * kp.z));
            float df = fmaf(-2.0f, dot, qs + kp.w);
            if (df <= fthr) {
                double X = (double)kp.x, Y = (double)kp.y, Z = (double)kp.z;
                double ks = X * X + Y * Y + Z * Z;          // same order as fp64 ref
                double dd = qdx * X + qdy * Y + qdz * Z;
                double de = qds + ks - 2.0 * dd;
                ins3d(de, m, A0, G0, A1, G1, A2, G2);
            }
        }
#pragma unroll
        for (int off = 1; off < 8; off <<= 1) {
            double e0 = __shfl_xor(A0, off), e1 = __shfl_xor(A1, off), e2 = __shfl_xor(A2, off);
            int    j0 = __shfl_xor(G0, off), j1 = __shfl_xor(G1, off), j2 = __shfl_xor(G2, off);
            ins3d(e0, j0, A0, G0, A1, G1, A2, G2);
            ins3d(e1, j1, A0, G0, A1, G1, A2, G2);
            ins3d(e2, j2, A0, G0, A1, G1, A2, G2);
        }
        E0 = A0; E1 = A1; E2 = A2;
        F0 = G0; F1 = G1; F2 = G2;
    }

    if (sub == 0) {
        double w0 = 1.0 / (E0 + 1e-8);
        double w1 = 1.0 / (E1 + 1e-8);
        double w2 = 1.0 / (E2 + 1e-8);
        double inv = 1.0 / (w0 + w1 + w2);
        size_t p = (size_t)b * N_ + n;
        idx3[p] = make_int4(F0, F1, F2, 0);
        wgt3[p] = make_float4((float)(w0 * inv), (float)(w1 * inv), (float)(w2 * inv), 0.f);
    }
}

// ---------------------------------------------------------------------------
// Weighted gather: wave per point, 8 points/wave, idx/wgt prefetch depth 1.
// Writes columns 256..767 of A_cat (P, 768) bf16.
// ---------------------------------------------------------------------------
__global__ __launch_bounds__(256) void gather_k(
    const int4* __restrict__ idx3, const float4* __restrict__ wgt3,
    const ushort_t* __restrict__ kfT, ushort_t* __restrict__ Acat) {
    int blk = blockIdx.x;             // 2048 blocks
    int b = blk >> 7;                 // 128 blocks per batch
    int n0 = (blk & 127) * 32;
    int lane = threadIdx.x & 63, wid = threadIdx.x >> 6;

    size_t pbase = (size_t)b * N_ + n0 + wid * 8;
    int4 id = idx3[pbase];
    float4 w = wgt3[pbase];
    for (int it = 0; it < 8; ++it) {
        int4 idn; float4 wn;
        if (it < 7) { idn = idx3[pbase + it + 1]; wn = wgt3[pbase + it + 1]; }
        const uint4* r0 = (const uint4*)(kfT + ((size_t)b * M_ + id.x) * C2_);
        const uint4* r1 = (const uint4*)(kfT + ((size_t)b * M_ + id.y) * C2_);
        const uint4* r2 = (const uint4*)(kfT + ((size_t)b * M_ + id.z) * C2_);
        uint4 v0 = r0[lane], v1 = r1[lane], v2 = r2[lane];
        const ushort_t* p0 = (const ushort_t*)&v0;
        const ushort_t* p1 = (const ushort_t*)&v1;
        const ushort_t* p2 = (const ushort_t*)&v2;
        uint4 o; ushort_t* po = (ushort_t*)&o;
        for (int j = 0; j < 8; ++j) {
            float f = w.x * b2f(p0[j]) + w.y * b2f(p1[j]) + w.z * b2f(p2[j]);
            po[j] = f2b(f);
        }
        ((uint4*)(Acat + (pbase + it) * K1_ + C1_))[lane] = o;
        id = idn; w = wn;
    }
}

// ---------------------------------------------------------------------------
// Unified GEMM: C(P,256) = A(P,K) * Bw(256,K)^T, bf16 MFMA.
// 128x256 tile, 8 waves (512 thr), grid = P/128 = 512 blocks = 2/CU resident.
// 3-buffer pipeline, prefetch depth 2, COUNTED vmcnt + raw s_barrier —
// loads stay in flight across barriers (T3/T4; __syncthreads would drain
// vmcnt(0) and serialize, which is what capped the previous version).
// Per-thread stage = 3 async16 (1 A + 2 B) -> steady-state vmcnt(6),
// tail vmcnt(3)/vmcnt(0). Staging is the ONLY VMEM in the loop, so the
// counts are exact. XOR swizzle as before (verified conflict-free).
// ---------------------------------------------------------------------------
__global__ __launch_bounds__(512, 4) void gemm_k(
    const ushort_t* __restrict__ A, const ushort_t* __restrict__ Bw,
    ushort_t* __restrict__ C, int K) {
    __shared__ ushort_t As[3][128 * 32];
    __shared__ ushort_t Bs[3][256 * 32];
    int t = threadIdx.x, lane = t & 63, wid = t >> 6;
    int wm = wid & 1, wn = wid >> 1;           // 2 x 4 wave grid -> 64x64 each
    int row0 = blockIdx.x * 128;
    int quad = lane >> 4, l15 = lane & 15;
    int srow = lane >> 2, kc = lane & 3;
    int kcs = kc ^ ((srow >> 1) & 3);          // swizzled source chunk
    int rsw = (l15 >> 1) & 3;                  // read-side swizzle key

    f32x4 acc[4][4] = {};

    auto stage = [&](int buf, int k0) {
        async16(A + ((size_t)(row0 + wid * 16 + srow)) * K + k0 + kcs * 8,
                &As[buf][wid * 16 * 32]);
#pragma unroll
        for (int j = 0; j < 2; ++j) {
            int rbase = wid * 32 + j * 16;
            async16(Bw + ((size_t)(rbase + srow)) * K + k0 + kcs * 8,
                    &Bs[buf][rbase * 32]);
        }
    };

    int nt = K >> 5;                 // 24 or 8
    stage(0, 0);
    stage(1, 32);

    int bi = 0;
    for (int it = 0; it < nt; ++it) {
        int pf = it + 2;
        if (pf < nt) stage(pf % 3, pf * 32);

        if (it < nt - 2)      asm volatile("s_waitcnt vmcnt(6)" ::: "memory");
        else if (it == nt - 2) asm volatile("s_waitcnt vmcnt(3)" ::: "memory");
        else                  asm volatile("s_waitcnt vmcnt(0)" ::: "memory");
        __builtin_amdgcn_s_barrier();          // all waves' tile-it loads landed
        asm volatile("" ::: "memory");

        s16x8 af[4], bfr[4];
#pragma unroll
        for (int i = 0; i < 4; ++i)
            af[i] = *(const s16x8*)&As[bi][(wm * 64 + i * 16 + l15) * 32 + ((quad ^ rsw) * 8)];
#pragma unroll
        for (int j = 0; j < 4; ++j)
            bfr[j] = *(const s16x8*)&Bs[bi][(wn * 64 + j * 16 + l15) * 32 + ((quad ^ rsw) * 8)];
#pragma unroll
        for (int i = 0; i < 4; ++i)
#pragma unroll
            for (int j = 0; j < 4; ++j)
                acc[i][j] = __builtin_amdgcn_mfma_f32_16x16x32_bf16(
                    af[i], bfr[j], acc[i][j], 0, 0, 0);

        asm volatile("" ::: "memory");
        __builtin_amdgcn_s_barrier();          // reads of buf bi done -> reusable
        asm volatile("" ::: "memory");
        bi = (bi + 1 == 3) ? 0 : bi + 1;
    }

    for (int i = 0; i < 4; ++i)
        for (int j = 0; j < 4; ++j)
            for (int r = 0; r < 4; ++r) {
                int m = row0 + wm * 64 + i * 16 + quad * 4 + r;
                int n = wn * 64 + j * 16 + l15;
                C[(size_t)m * H_ + n] = f2b(acc[i][j][r]);
            }
}

// ---------------------------------------------------------------------------
__global__ __launch_bounds__(256) void stats_k(
    const ushort_t* __restrict__ x, float* __restrict__ sum, float* __restrict__ sq) {
    int t = threadIdx.x;
    int r0 = blockIdx.x * 256;
    float s = 0.f, q = 0.f;
    for (int r = 0; r < 256; ++r) {
        float v = b2f(x[(size_t)(r0 + r) * 256 + t]);
        s += v; q += v * v;
    }
    atomicAdd(&sum[t], s);
    atomicAdd(&sq[t], q);
}

__global__ __launch_bounds__(256) void coef_k(
    const float* __restrict__ sum, const float* __restrict__ sq,
    const float* __restrict__ g, const float* __restrict__ bt,
    float* __restrict__ a, float* __restrict__ c) {
    int t = threadIdx.x;
    float mean = sum[t] * (1.0f / P_);
    float var  = sq[t] * (1.0f / P_) - mean * mean;
    float ai = g[t] * rsqrtf(var + 1e-5f);
    a[t] = ai;
    c[t] = bt[t] - mean * ai;
}

// BN + ReLU elementwise: x1 (P,256) bf16 -> h1 bf16, one uint4 (8 elems)/thread
__global__ __launch_bounds__(256) void bnrelu_k(
    const uint4* __restrict__ x, const float* __restrict__ a,
    const float* __restrict__ c, uint4* __restrict__ h) {
    size_t i = (size_t)blockIdx.x * 256 + threadIdx.x;   // 2,097,152 uint4s
    uint4 v = x[i];
    int chb = (int)((i * 8) & 255);
    const ushort_t* pv = (const ushort_t*)&v;
    uint4 o; ushort_t* po = (ushort_t*)&o;
    for (int j = 0; j < 8; ++j) {
        float f = b2f(pv[j]);
        f = a[chb + j] * f + c[chb + j];
        po[j] = f2b(fmaxf(f, 0.0f));
    }
    h[i] = o;
}

// BN + ReLU + transpose: x2 (P,256) bf16 -> out (B,256,N) f32, 64x64 tiles
__global__ __launch_bounds__(256) void final_k(
    const ushort_t* __restrict__ x2, const float* __restrict__ a,
    const float* __restrict__ c, float* __restrict__ out) {
    __shared__ float tile[64][65];
    int n0 = blockIdx.x * 64, c0 = blockIdx.y * 64, b = blockIdx.z;
    int t = threadIdx.x;
    {
        int cl = t & 63, pb = (t >> 6) * 16;
        float av = a[c0 + cl], cv = c[c0 + cl];
        for (int i = 0; i < 16; ++i) {
            float v = b2f(x2[((size_t)b * N_ + n0 + pb + i) * H_ + c0 + cl]);
            tile[cl][pb + i] = fmaxf(av * v + cv, 0.0f);
        }
    }
    __syncthreads();
    {
        int nl = t & 63, cb = (t >> 6) * 16;
        for (int i = 0; i < 16; ++i)
            out[((size_t)b * H_ + c0 + cb + i) * N_ + n0 + nl] = tile[cb + i][nl];
    }
}

// ---------------------------------------------------------------------------
extern "C" void kernel_launch(void* const* d_in, const int* in_sizes, int n_in,
                              void* d_out, int out_size, void* d_ws, size_t ws_size,
                              hipStream_t stream) {
    const float* unknown = (const float*)d_in[0];
    const float* known   = (const float*)d_in[1];
    const float* uf      = (const float*)d_in[2];
    const float* kf      = (const float*)d_in[3];
    const float* w1      = (const float*)d_in[4];
    const float* g1      = (const float*)d_in[5];
    const float* b1      = (const float*)d_in[6];
    const float* w2      = (const float*)d_in[7];
    const float* g2      = (const float*)d_in[8];
    const float* b2      = (const float*)d_in[9];
    float* out = (float*)d_out;

    char* ws = (char*)d_ws;
    // [0, 8K): stats — sum1,sq1,sum2,sq2,a1,c1,a2,c2 (8 x 256 f32)
    float* sum1 = (float*)ws;
    float* sq1  = sum1 + 256;
    float* sum2 = sum1 + 512;
    float* sq2  = sum1 + 768;
    float* a1   = sum1 + 1024;
    float* c1   = sum1 + 1280;
    float* a2   = sum1 + 1536;
    float* c2   = sum1 + 1792;
    // [8K, ~520K): converted weights
    ushort_t* w1b = (ushort_t*)(ws + 8192);                        // 384 KB
    ushort_t* w2b = (ushort_t*)(ws + 8192 + (size_t)H_ * K1_ * 2); // 128 KB
    const size_t MB = 1024 * 1024;
    // Lifetimes (stream-serialized):
    //   Acat [1,97): written by tuf_k (cols 0..255) + gather_k (256..767),
    //                read by gemm1 — dead after.
    //   kfT  [97,113): tkf_k -> gather_k, dead after gather.
    //   idx3/wgt3 [113,115): knn -> gather, dead after gather.
    //   x1   [97,129): written by gemm1 (kfT/idx3/wgt3 dead by then).
    //   h1   [1,33):  written by bnrelu (Acat dead), read by gemm2.
    //   x2   [33,65): written by gemm2, read by stats2/final.
    // Peak 129 MB.
    ushort_t* Acat = (ushort_t*)(ws + 1 * MB);      // 96 MB
    ushort_t* kfT  = (ushort_t*)(ws + 97 * MB);     // 16 MB
    int4*   idx3 = (int4*)(ws + 113 * MB);          // 1 MB
    float4* wgt3 = (float4*)(ws + 114 * MB);        // 1 MB
    ushort_t* x1   = (ushort_t*)(ws + 97 * MB);     // 32 MB
    ushort_t* h1   = (ushort_t*)(ws + 1 * MB);      // 32 MB
    ushort_t* x2   = (ushort_t*)(ws + 33 * MB);     // 32 MB

    zero_k<<<8, 256, 0, stream>>>(sum1);
    cvtw_k<<<1024, 256, 0, stream>>>(w1, w2, w1b, w2b);
    tkf_k<<<dim3(16, 8, 16), 256, 0, stream>>>(kf, kfT);
    tuf_k<<<dim3(64, 4, 16), 256, 0, stream>>>(uf, Acat);
    knn_k<<<2048, 256, 0, stream>>>(unknown, known, idx3, wgt3);
    gather_k<<<2048, 256, 0, stream>>>(idx3, wgt3, kfT, Acat);
    gemm_k<<<512, 512, 0, stream>>>(Acat, w1b, x1, K1_);
    stats_k<<<256, 256, 0, stream>>>(x1, sum1, sq1);
    coef_k<<<1, 256, 0, stream>>>(sum1, sq1, g1, b1, a1, c1);
    bnrelu_k<<<8192, 256, 0, stream>>>((const uint4*)x1, a1, c1, (uint4*)h1);
    gemm_k<<<512, 512, 0, stream>>>(h1, w2b, x2, H_);
    stats_k<<<256, 256, 0, stream>>>(x2, sum2, sq2);
    coef_k<<<1, 256, 0, stream>>>(sum2, sq2, g2, b2, a2, c2);
    final_k<<<dim3(64, 4, 16), 256, 0, stream>>>(x2, a2, c2, out);
}

// Round 5
// 348.851 us; speedup vs baseline: 1.1535x; 1.0587x over previous
//
#include <hip/hip_runtime.h>
#include <stdint.h>

#define B_   16
#define N_   4096
#define M_   1024
#define C1_  256
#define C2_  512
#define H_   256
#define K1_  768      // C1+C2
#define P_   65536    // B*N

typedef unsigned int  uint_t;
typedef unsigned short ushort_t;
typedef __attribute__((ext_vector_type(4))) float f32x4;
typedef __attribute__((ext_vector_type(8))) short s16x8;

__device__ __forceinline__ float b2f(ushort_t u) {
    union { uint_t i; float f; } v; v.i = ((uint_t)u) << 16; return v.f;
}
__device__ __forceinline__ ushort_t f2b(float f) {
    union { float f; uint_t i; } v; v.f = f;
    uint_t x = v.i;
    return (ushort_t)((x + 0x7fffu + ((x >> 16) & 1u)) >> 16);  // RNE
}

__device__ __forceinline__ void async16(const void* g, void* l) {
    __builtin_amdgcn_global_load_lds(
        (const __attribute__((address_space(1))) uint_t*)g,
        (__attribute__((address_space(3))) uint_t*)l, 16, 0, 0);
}

// ---------------------------------------------------------------------------
__global__ __launch_bounds__(256) void zero_k(float* __restrict__ p) {
    p[blockIdx.x * 256 + threadIdx.x] = 0.0f;
}

// ---------------------------------------------------------------------------
// Convert w1 (256x768 f32) and w2 (256x256 f32) to bf16.
// ---------------------------------------------------------------------------
__global__ __launch_bounds__(256) void cvtw_k(
    const float* __restrict__ w1, const float* __restrict__ w2,
    ushort_t* __restrict__ w1b, ushort_t* __restrict__ w2b) {
    int t = blockIdx.x * 256 + threadIdx.x;   // 262144 total
    if (t < H_ * K1_) w1b[t] = f2b(w1[t]);
    else { int u = t - H_ * K1_; w2b[u] = f2b(w2[u]); }
}

// ---------------------------------------------------------------------------
// known_feats (B, 512, 1024) f32 -> kfT (B, 1024, 512) bf16, 64x64 LDS tiles
// ---------------------------------------------------------------------------
__global__ __launch_bounds__(256) void tkf_k(
    const float* __restrict__ in, ushort_t* __restrict__ out) {
    __shared__ ushort_t tile[64][65];
    int m0 = blockIdx.x * 64, c0 = blockIdx.y * 64, b = blockIdx.z;
    int t = threadIdx.x;
    {
        int ml = t & 63, cb = (t >> 6) * 16;
        const float* ip = in + ((size_t)b * C2_ + c0) * M_ + m0;
        for (int i = 0; i < 16; ++i)
            tile[cb + i][ml] = f2b(ip[(size_t)(cb + i) * M_ + ml]);
    }
    __syncthreads();
    {
        int cl = t & 63, mb = (t >> 6) * 16;
        for (int i = 0; i < 16; ++i)
            out[((size_t)b * M_ + m0 + mb + i) * C2_ + c0 + cl] = tile[cl][mb + i];
    }
}

// ---------------------------------------------------------------------------
// uf (B, 256, 4096) f32 -> A_cat (P, 768) bf16 columns 0..255, 64x64 tiles.
// Same f2b RNE as the old in-GEMM pack -> bit-identical A values.
// ---------------------------------------------------------------------------
__global__ __launch_bounds__(256) void tuf_k(
    const float* __restrict__ in, ushort_t* __restrict__ out) {
    __shared__ ushort_t tile[64][65];
    int n0 = blockIdx.x * 64, c0 = blockIdx.y * 64, b = blockIdx.z;
    int t = threadIdx.x;
    {
        int nl = t & 63, cb = (t >> 6) * 16;
        const float* ip = in + ((size_t)b * C1_ + c0) * N_ + n0;
        for (int i = 0; i < 16; ++i)
            tile[cb + i][nl] = f2b(ip[(size_t)(cb + i) * N_ + nl]);
    }
    __syncthreads();
    {
        int cl = t & 63, pb = (t >> 6) * 16;
        for (int i = 0; i < 16; ++i)
            out[((size_t)b * N_ + n0 + pb + i) * K1_ + c0 + cl] = tile[cl][pb + i];
    }
}

// ---------------------------------------------------------------------------
// 3-NN, 8 threads per point.
// Hot loop: (d,m) packed into one u32 key = (bits(d)&0xFFFFFC00)|m
// (d>=0 clamped -> uint order == float order; m<1024 in low 10 bits ->
// lexicographic (d_trunc, m) = reference's stable tie-break). Top-4 kept
// with a pure v_min_u32/v_max_u32 sorting network: 7 ops, no compares,
// no cndmask, no index registers. Truncation (2^-14 rel) is absorbed by
// the ambiguity margin (1e-4 + 2.5e-4*d): flagged points take the exact
// fp32-rescan + fp64-lexicographic fallback (identical to prior rounds).
// ---------------------------------------------------------------------------
__device__ __forceinline__ uint_t umin_(uint_t a, uint_t b) { return a < b ? a : b; }
__device__ __forceinline__ uint_t umax_(uint_t a, uint_t b) { return a > b ? a : b; }

// insert key into sorted k0<=k1<=k2<=k3, keep 4 smallest (7 min/max ops)
__device__ __forceinline__ void insk(uint_t key,
        uint_t& k0, uint_t& k1, uint_t& k2, uint_t& k3) {
    uint_t t2 = umax_(k2, key);
    uint_t t1 = umax_(k1, key);
    uint_t t0 = umax_(k0, key);
    k3 = umin_(k3, t2);
    k2 = umin_(k2, t1);
    k1 = umin_(k1, t0);
    k0 = umin_(k0, key);
}

__device__ __forceinline__ void ins3d(double d, int m,
                                      double& d0, int& i0, double& d1, int& i1,
                                      double& d2, int& i2) {
    if (d < d2 || (d == d2 && m < i2)) {
        d2 = d; i2 = m;
        if (d2 < d1 || (d2 == d1 && i2 < i1)) { double td = d1; d1 = d2; d2 = td; int ti = i1; i1 = i2; i2 = ti; }
        if (d1 < d0 || (d1 == d0 && i1 < i0)) { double td = d0; d0 = d1; d1 = td; int ti = i0; i0 = i1; i1 = ti; }
    }
}

__global__ __launch_bounds__(256) void knn_k(
    const float* __restrict__ unknown, const float* __restrict__ known,
    int4* __restrict__ idx3, float4* __restrict__ wgt3) {
    __shared__ float4 kpt[M_];             // (x, y, z, |k|^2 fp32) — 16 KB
    int b = blockIdx.x >> 7;               // 2048 blocks, 128 per batch
    int n0 = (blockIdx.x & 127) * 32;      // 32 points per block
    int t = threadIdx.x;
    int pl = t >> 3;                       // point-local 0..31
    int sub = t & 7;                       // candidate slice 0..7

    for (int m = t; m < M_; m += 256) {
        float x = known[((size_t)b * M_ + m) * 3 + 0];
        float y = known[((size_t)b * M_ + m) * 3 + 1];
        float z = known[((size_t)b * M_ + m) * 3 + 2];
        kpt[m] = make_float4(x, y, z, x * x + y * y + z * z);
    }
    __syncthreads();

    int n = n0 + pl;
    float qx = unknown[((size_t)b * N_ + n) * 3 + 0];
    float qy = unknown[((size_t)b * N_ + n) * 3 + 1];
    float qz = unknown[((size_t)b * N_ + n) * 3 + 2];
    float qs = qx * qx + qy * qy + qz * qz;

    const uint_t DMASK = 0xFFFFFC00u;
    uint_t K0[2], K1[2], K2[2], K3[2];
#pragma unroll
    for (int s = 0; s < 2; ++s) {
        K0[s] = 0xFFFFFFFFu; K1[s] = 0xFFFFFFFFu;
        K2[s] = 0xFFFFFFFFu; K3[s] = 0xFFFFFFFFu;
    }

#pragma unroll 4
    for (int j = 0; j < 64; ++j) {
#pragma unroll
        for (int s = 0; s < 2; ++s) {
            int mb = 8 * (2 * j + s);        // interleaved: distinct banks per sub
            float4 kp = kpt[mb + sub];
            float dot = fmaf(qx, kp.x, fmaf(qy, kp.y, qz * kp.z));
            float d = fmaf(-2.0f, dot, qs + kp.w);
            d = fmaxf(d, 0.0f);              // squared distance: clamp fp noise
            uint_t key = (__float_as_uint(d) & DMASK) | (uint_t)mb | (uint_t)sub;
            insk(key, K0[s], K1[s], K2[s], K3[s]);
        }
    }
    // merge stream 1 into 0
    insk(K0[1], K0[0], K1[0], K2[0], K3[0]);
    insk(K1[1], K0[0], K1[0], K2[0], K3[0]);
    insk(K2[1], K0[0], K1[0], K2[0], K3[0]);
    insk(K3[1], K0[0], K1[0], K2[0], K3[0]);

    // merge across the 8 subs (lane bits 0..2) — symmetric butterfly
#pragma unroll
    for (int off = 1; off < 8; off <<= 1) {
        uint_t e0 = (uint_t)__shfl_xor((int)K0[0], off);
        uint_t e1 = (uint_t)__shfl_xor((int)K1[0], off);
        uint_t e2 = (uint_t)__shfl_xor((int)K2[0], off);
        uint_t e3 = (uint_t)__shfl_xor((int)K3[0], off);
        insk(e0, K0[0], K1[0], K2[0], K3[0]);
        insk(e1, K0[0], K1[0], K2[0], K3[0]);
        insk(e2, K0[0], K1[0], K2[0], K3[0]);
        insk(e3, K0[0], K1[0], K2[0], K3[0]);
    }
    // all 8 lanes of a point now hold the same top-4 keys

    float d0t = __uint_as_float(K0[0] & DMASK);
    float d1t = __uint_as_float(K1[0] & DMASK);
    float d2t = __uint_as_float(K2[0] & DMASK);
    float d3t = __uint_as_float(K3[0] & DMASK);
    // margin covers truncation (2^-14 rel, both values) + fp32 eval divergence
    float margin = fmaf(d3t, 2.5e-4f, 1.0e-4f);
    bool flagged = (d3t - d2t) <= margin;

    double E0, E1, E2; int F0, F1, F2;
    if (!flagged) {
        E0 = (double)d0t; E1 = (double)d1t; E2 = (double)d2t;
        F0 = (int)(K0[0] & 0x3FFu);
        F1 = (int)(K1[0] & 0x3FFu);
        F2 = (int)(K2[0] & 0x3FFu);
    } else {
        // exact fallback: fp32 rescan + fp64 lexicographic insert for the
        // few candidates that can possibly be in the true top-3.
        float fthr = d2t + margin;
        double qdx = (double)qx, qdy = (double)qy, qdz = (double)qz;
        double qds = qdx * qdx + qdy * qdy + qdz * qdz;
        double A0 = 1e300, A1 = 1e300, A2 = 1e300;
        int    G0 = 0x7fffffff, G1 = 0x7fffffff, G2 = 0x7fffffff;
        for (int m = sub; m < M_; m += 8) {
            float4 kp = kpt[m];
            float dot = fmaf(qx, kp.x, fmaf(qy, kp.y, qz * kp.z));
            float df = fmaf(-2.0f, dot, qs + kp.w);
            if (df <= fthr) {
                double X = (double)kp.x, Y = (double)kp.y, Z = (double)kp.z;
                double ks = X * X + Y * Y + Z * Z;          // same order as fp64 ref
                double dd = qdx * X + qdy * Y + qdz * Z;
                double de = qds + ks - 2.0 * dd;
                ins3d(de, m, A0, G0, A1, G1, A2, G2);
            }
        }
#pragma unroll
        for (int off = 1; off < 8; off <<= 1) {
            double e0 = __shfl_xor(A0, off), e1 = __shfl_xor(A1, off), e2 = __shfl_xor(A2, off);
            int    j0 = __shfl_xor(G0, off), j1 = __shfl_xor(G1, off), j2 = __shfl_xor(G2, off);
            ins3d(e0, j0, A0, G0, A1, G1, A2, G2);
            ins3d(e1, j1, A0, G0, A1, G1, A2, G2);
            ins3d(e2, j2, A0, G0, A1, G1, A2, G2);
        }
        E0 = A0; E1 = A1; E2 = A2;
        F0 = G0; F1 = G1; F2 = G2;
    }

    if (sub == 0) {
        double w0 = 1.0 / (E0 + 1e-8);
        double w1 = 1.0 / (E1 + 1e-8);
        double w2 = 1.0 / (E2 + 1e-8);
        double inv = 1.0 / (w0 + w1 + w2);
        size_t p = (size_t)b * N_ + n;
        idx3[p] = make_int4(F0, F1, F2, 0);
        wgt3[p] = make_float4((float)(w0 * inv), (float)(w1 * inv), (float)(w2 * inv), 0.f);
    }
}

// ---------------------------------------------------------------------------
// Weighted gather: wave per point, 8 points/wave, idx/wgt prefetch depth 1.
// Writes columns 256..767 of A_cat (P, 768) bf16.
// ---------------------------------------------------------------------------
__global__ __launch_bounds__(256) void gather_k(
    const int4* __restrict__ idx3, const float4* __restrict__ wgt3,
    const ushort_t* __restrict__ kfT, ushort_t* __restrict__ Acat) {
    int blk = blockIdx.x;             // 2048 blocks
    int b = blk >> 7;                 // 128 blocks per batch
    int n0 = (blk & 127) * 32;
    int lane = threadIdx.x & 63, wid = threadIdx.x >> 6;

    size_t pbase = (size_t)b * N_ + n0 + wid * 8;
    int4 id = idx3[pbase];
    float4 w = wgt3[pbase];
    for (int it = 0; it < 8; ++it) {
        int4 idn; float4 wn;
        if (it < 7) { idn = idx3[pbase + it + 1]; wn = wgt3[pbase + it + 1]; }
        const uint4* r0 = (const uint4*)(kfT + ((size_t)b * M_ + id.x) * C2_);
        const uint4* r1 = (const uint4*)(kfT + ((size_t)b * M_ + id.y) * C2_);
        const uint4* r2 = (const uint4*)(kfT + ((size_t)b * M_ + id.z) * C2_);
        uint4 v0 = r0[lane], v1 = r1[lane], v2 = r2[lane];
        const ushort_t* p0 = (const ushort_t*)&v0;
        const ushort_t* p1 = (const ushort_t*)&v1;
        const ushort_t* p2 = (const ushort_t*)&v2;
        uint4 o; ushort_t* po = (ushort_t*)&o;
        for (int j = 0; j < 8; ++j) {
            float f = w.x * b2f(p0[j]) + w.y * b2f(p1[j]) + w.z * b2f(p2[j]);
            po[j] = f2b(f);
        }
        ((uint4*)(Acat + (pbase + it) * K1_ + C1_))[lane] = o;
        id = idn; w = wn;
    }
}

// ---------------------------------------------------------------------------
// Unified GEMM: C(P,256) = A(P,K) * Bw(256,K)^T, bf16 MFMA.
// 128x256 tile, 8 waves (512 thr), grid = P/128 = 512 blocks = 2/CU resident.
// 3-buffer pipeline, prefetch depth 2, COUNTED vmcnt + raw s_barrier —
// loads stay in flight across barriers (T3/T4). Per-thread stage = 3
// async16 (1 A + 2 B) -> steady-state vmcnt(6), tail vmcnt(3)/vmcnt(0).
// Staging is the ONLY VMEM in the loop, so the counts are exact.
// XOR swizzle on both sides (verified conflict-free).
// ---------------------------------------------------------------------------
__global__ __launch_bounds__(512, 4) void gemm_k(
    const ushort_t* __restrict__ A, const ushort_t* __restrict__ Bw,
    ushort_t* __restrict__ C, int K) {
    __shared__ ushort_t As[3][128 * 32];
    __shared__ ushort_t Bs[3][256 * 32];
    int t = threadIdx.x, lane = t & 63, wid = t >> 6;
    int wm = wid & 1, wn = wid >> 1;           // 2 x 4 wave grid -> 64x64 each
    int row0 = blockIdx.x * 128;
    int quad = lane >> 4, l15 = lane & 15;
    int srow = lane >> 2, kc = lane & 3;
    int kcs = kc ^ ((srow >> 1) & 3);          // swizzled source chunk
    int rsw = (l15 >> 1) & 3;                  // read-side swizzle key

    f32x4 acc[4][4] = {};

    auto stage = [&](int buf, int k0) {
        async16(A + ((size_t)(row0 + wid * 16 + srow)) * K + k0 + kcs * 8,
                &As[buf][wid * 16 * 32]);
#pragma unroll
        for (int j = 0; j < 2; ++j) {
            int rbase = wid * 32 + j * 16;
            async16(Bw + ((size_t)(rbase + srow)) * K + k0 + kcs * 8,
                    &Bs[buf][rbase * 32]);
        }
    };

    int nt = K >> 5;                 // 24 or 8
    stage(0, 0);
    stage(1, 32);

    int bi = 0;
    for (int it = 0; it < nt; ++it) {
        int pf = it + 2;
        if (pf < nt) stage(pf % 3, pf * 32);

        if (it < nt - 2)      asm volatile("s_waitcnt vmcnt(6)" ::: "memory");
        else if (it == nt - 2) asm volatile("s_waitcnt vmcnt(3)" ::: "memory");
        else                  asm volatile("s_waitcnt vmcnt(0)" ::: "memory");
        __builtin_amdgcn_s_barrier();          // all waves' tile-it loads landed
        asm volatile("" ::: "memory");

        s16x8 af[4], bfr[4];
#pragma unroll
        for (int i = 0; i < 4; ++i)
            af[i] = *(const s16x8*)&As[bi][(wm * 64 + i * 16 + l15) * 32 + ((quad ^ rsw) * 8)];
#pragma unroll
        for (int j = 0; j < 4; ++j)
            bfr[j] = *(const s16x8*)&Bs[bi][(wn * 64 + j * 16 + l15) * 32 + ((quad ^ rsw) * 8)];
#pragma unroll
        for (int i = 0; i < 4; ++i)
#pragma unroll
            for (int j = 0; j < 4; ++j)
                acc[i][j] = __builtin_amdgcn_mfma_f32_16x16x32_bf16(
                    af[i], bfr[j], acc[i][j], 0, 0, 0);

        asm volatile("" ::: "memory");
        __builtin_amdgcn_s_barrier();          // reads of buf bi done -> reusable
        asm volatile("" ::: "memory");
        bi = (bi + 1 == 3) ? 0 : bi + 1;
    }

    for (int i = 0; i < 4; ++i)
        for (int j = 0; j < 4; ++j)
            for (int r = 0; r < 4; ++r) {
                int m = row0 + wm * 64 + i * 16 + quad * 4 + r;
                int n = wn * 64 + j * 16 + l15;
                C[(size_t)m * H_ + n] = f2b(acc[i][j][r]);
            }
}

// ---------------------------------------------------------------------------
__global__ __launch_bounds__(256) void stats_k(
    const ushort_t* __restrict__ x, float* __restrict__ sum, float* __restrict__ sq) {
    int t = threadIdx.x;
    int r0 = blockIdx.x * 256;
    float s = 0.f, q = 0.f;
    for (int r = 0; r < 256; ++r) {
        float v = b2f(x[(size_t)(r0 + r) * 256 + t]);
        s += v; q += v * v;
    }
    atomicAdd(&sum[t], s);
    atomicAdd(&sq[t], q);
}

__global__ __launch_bounds__(256) void coef_k(
    const float* __restrict__ sum, const float* __restrict__ sq,
    const float* __restrict__ g, const float* __restrict__ bt,
    float* __restrict__ a, float* __restrict__ c) {
    int t = threadIdx.x;
    float mean = sum[t] * (1.0f / P_);
    float var  = sq[t] * (1.0f / P_) - mean * mean;
    float ai = g[t] * rsqrtf(var + 1e-5f);
    a[t] = ai;
    c[t] = bt[t] - mean * ai;
}

// BN + ReLU elementwise: x1 (P,256) bf16 -> h1 bf16, one uint4 (8 elems)/thread
__global__ __launch_bounds__(256) void bnrelu_k(
    const uint4* __restrict__ x, const float* __restrict__ a,
    const float* __restrict__ c, uint4* __restrict__ h) {
    size_t i = (size_t)blockIdx.x * 256 + threadIdx.x;   // 2,097,152 uint4s
    uint4 v = x[i];
    int chb = (int)((i * 8) & 255);
    const ushort_t* pv = (const ushort_t*)&v;
    uint4 o; ushort_t* po = (ushort_t*)&o;
    for (int j = 0; j < 8; ++j) {
        float f = b2f(pv[j]);
        f = a[chb + j] * f + c[chb + j];
        po[j] = f2b(fmaxf(f, 0.0f));
    }
    h[i] = o;
}

// BN + ReLU + transpose: x2 (P,256) bf16 -> out (B,256,N) f32, 64x64 tiles
__global__ __launch_bounds__(256) void final_k(
    const ushort_t* __restrict__ x2, const float* __restrict__ a,
    const float* __restrict__ c, float* __restrict__ out) {
    __shared__ float tile[64][65];
    int n0 = blockIdx.x * 64, c0 = blockIdx.y * 64, b = blockIdx.z;
    int t = threadIdx.x;
    {
        int cl = t & 63, pb = (t >> 6) * 16;
        float av = a[c0 + cl], cv = c[c0 + cl];
        for (int i = 0; i < 16; ++i) {
            float v = b2f(x2[((size_t)b * N_ + n0 + pb + i) * H_ + c0 + cl]);
            tile[cl][pb + i] = fmaxf(av * v + cv, 0.0f);
        }
    }
    __syncthreads();
    {
        int nl = t & 63, cb = (t >> 6) * 16;
        for (int i = 0; i < 16; ++i)
            out[((size_t)b * H_ + c0 + cb + i) * N_ + n0 + nl] = tile[cb + i][nl];
    }
}

// ---------------------------------------------------------------------------
extern "C" void kernel_launch(void* const* d_in, const int* in_sizes, int n_in,
                              void* d_out, int out_size, void* d_ws, size_t ws_size,
                              hipStream_t stream) {
    const float* unknown = (const float*)d_in[0];
    const float* known   = (const float*)d_in[1];
    const float* uf      = (const float*)d_in[2];
    const float* kf      = (const float*)d_in[3];
    const float* w1      = (const float*)d_in[4];
    const float* g1      = (const float*)d_in[5];
    const float* b1      = (const float*)d_in[6];
    const float* w2      = (const float*)d_in[7];
    const float* g2      = (const float*)d_in[8];
    const float* b2      = (const float*)d_in[9];
    float* out = (float*)d_out;

    char* ws = (char*)d_ws;
    // [0, 8K): stats — sum1,sq1,sum2,sq2,a1,c1,a2,c2 (8 x 256 f32)
    float* sum1 = (float*)ws;
    float* sq1  = sum1 + 256;
    float* sum2 = sum1 + 512;
    float* sq2  = sum1 + 768;
    float* a1   = sum1 + 1024;
    float* c1   = sum1 + 1280;
    float* a2   = sum1 + 1536;
    float* c2   = sum1 + 1792;
    // [8K, ~520K): converted weights
    ushort_t* w1b = (ushort_t*)(ws + 8192);                        // 384 KB
    ushort_t* w2b = (ushort_t*)(ws + 8192 + (size_t)H_ * K1_ * 2); // 128 KB
    const size_t MB = 1024 * 1024;
    // Lifetimes (stream-serialized):
    //   Acat [1,97): written by tuf_k (cols 0..255) + gather_k (256..767),
    //                read by gemm1 — dead after.
    //   kfT  [97,113): tkf_k -> gather_k, dead after gather.
    //   idx3/wgt3 [113,115): knn -> gather, dead after gather.
    //   x1   [97,129): written by gemm1 (kfT/idx3/wgt3 dead by then).
    //   h1   [1,33):  written by bnrelu (Acat dead), read by gemm2.
    //   x2   [33,65): written by gemm2, read by stats2/final.
    // Peak 129 MB.
    ushort_t* Acat = (ushort_t*)(ws + 1 * MB);      // 96 MB
    ushort_t* kfT  = (ushort_t*)(ws + 97 * MB);     // 16 MB
    int4*   idx3 = (int4*)(ws + 113 * MB);          // 1 MB
    float4* wgt3 = (float4*)(ws + 114 * MB);        // 1 MB
    ushort_t* x1   = (ushort_t*)(ws + 97 * MB);     // 32 MB
    ushort_t* h1   = (ushort_t*)(ws + 1 * MB);      // 32 MB
    ushort_t* x2   = (ushort_t*)(ws + 33 * MB);     // 32 MB

    zero_k<<<8, 256, 0, stream>>>(sum1);
    cvtw_k<<<1024, 256, 0, stream>>>(w1, w2, w1b, w2b);
    tkf_k<<<dim3(16, 8, 16), 256, 0, stream>>>(kf, kfT);
    tuf_k<<<dim3(64, 4, 16), 256, 0, stream>>>(uf, Acat);
    knn_k<<<2048, 256, 0, stream>>>(unknown, known, idx3, wgt3);
    gather_k<<<2048, 256, 0, stream>>>(idx3, wgt3, kfT, Acat);
    gemm_k<<<512, 512, 0, stream>>>(Acat, w1b, x1, K1_);
    stats_k<<<256, 256, 0, stream>>>(x1, sum1, sq1);
    coef_k<<<1, 256, 0, stream>>>(sum1, sq1, g1, b1, a1, c1);
    bnrelu_k<<<8192, 256, 0, stream>>>((const uint4*)x1, a1, c1, (uint4*)h1);
    gemm_k<<<512, 512, 0, stream>>>(h1, w2b, x2, H_);
    stats_k<<<256, 256, 0, stream>>>(x2, sum2, sq2);
    coef_k<<<1, 256, 0, stream>>>(sum2, sq2, g2, b2, a2, c2);
    final_k<<<dim3(64, 4, 16), 256, 0, stream>>>(x2, a2, c2, out);
}

// Round 7
// 347.264 us; speedup vs baseline: 1.1587x; 1.0046x over previous
//
#include <hip/hip_runtime.h>
#include <stdint.h>

#define B_   16
#define N_   4096
#define M_   1024
#define C1_  256
#define C2_  512
#define H_   256
#define K1_  768      // C1+C2
#define P_   65536    // B*N

typedef unsigned int  uint_t;
typedef unsigned short ushort_t;
typedef __attribute__((ext_vector_type(4))) float f32x4;
typedef __attribute__((ext_vector_type(8))) short s16x8;

__device__ __forceinline__ float b2f(ushort_t u) {
    union { uint_t i; float f; } v; v.i = ((uint_t)u) << 16; return v.f;
}
__device__ __forceinline__ ushort_t f2b(float f) {
    union { float f; uint_t i; } v; v.f = f;
    uint_t x = v.i;
    return (ushort_t)((x + 0x7fffu + ((x >> 16) & 1u)) >> 16);  // RNE
}

__device__ __forceinline__ void async16(const void* g, void* l) {
    __builtin_amdgcn_global_load_lds(
        (const __attribute__((address_space(1))) uint_t*)g,
        (__attribute__((address_space(3))) uint_t*)l, 16, 0, 0);
}

// ---------------------------------------------------------------------------
__global__ __launch_bounds__(256) void zero_k(float* __restrict__ p) {
    p[blockIdx.x * 256 + threadIdx.x] = 0.0f;
}

// ---------------------------------------------------------------------------
// Convert w1 (256x768 f32) and w2 (256x256 f32) to bf16.
// ---------------------------------------------------------------------------
__global__ __launch_bounds__(256) void cvtw_k(
    const float* __restrict__ w1, const float* __restrict__ w2,
    ushort_t* __restrict__ w1b, ushort_t* __restrict__ w2b) {
    int t = blockIdx.x * 256 + threadIdx.x;   // 262144 total
    if (t < H_ * K1_) w1b[t] = f2b(w1[t]);
    else { int u = t - H_ * K1_; w2b[u] = f2b(w2[u]); }
}

// ---------------------------------------------------------------------------
// known_feats (B, 512, 1024) f32 -> kfT (B, 1024, 512) bf16, 64x64 LDS tiles
// ---------------------------------------------------------------------------
__global__ __launch_bounds__(256) void tkf_k(
    const float* __restrict__ in, ushort_t* __restrict__ out) {
    __shared__ ushort_t tile[64][65];
    int m0 = blockIdx.x * 64, c0 = blockIdx.y * 64, b = blockIdx.z;
    int t = threadIdx.x;
    {
        int ml = t & 63, cb = (t >> 6) * 16;
        const float* ip = in + ((size_t)b * C2_ + c0) * M_ + m0;
        for (int i = 0; i < 16; ++i)
            tile[cb + i][ml] = f2b(ip[(size_t)(cb + i) * M_ + ml]);
    }
    __syncthreads();
    {
        int cl = t & 63, mb = (t >> 6) * 16;
        for (int i = 0; i < 16; ++i)
            out[((size_t)b * M_ + m0 + mb + i) * C2_ + c0 + cl] = tile[cl][mb + i];
    }
}

// ---------------------------------------------------------------------------
// uf (B, 256, 4096) f32 -> A_cat (P, 768) bf16 columns 0..255, 64x64 tiles.
// Same f2b RNE as the old in-GEMM pack -> bit-identical A values.
// ---------------------------------------------------------------------------
__global__ __launch_bounds__(256) void tuf_k(
    const float* __restrict__ in, ushort_t* __restrict__ out) {
    __shared__ ushort_t tile[64][65];
    int n0 = blockIdx.x * 64, c0 = blockIdx.y * 64, b = blockIdx.z;
    int t = threadIdx.x;
    {
        int nl = t & 63, cb = (t >> 6) * 16;
        const float* ip = in + ((size_t)b * C1_ + c0) * N_ + n0;
        for (int i = 0; i < 16; ++i)
            tile[cb + i][nl] = f2b(ip[(size_t)(cb + i) * N_ + nl]);
    }
    __syncthreads();
    {
        int cl = t & 63, pb = (t >> 6) * 16;
        for (int i = 0; i < 16; ++i)
            out[((size_t)b * N_ + n0 + pb + i) * K1_ + c0 + cl] = tile[cl][pb + i];
    }
}

// ---------------------------------------------------------------------------
// 3-NN. 16 candidate-subs x 2 queries per thread — each kpt LDS read serves
// 2 evals, halving the LDS-issue bound. Keys: (bits(d)&0xFFFFFC00)|m,
// top-4 via u32 min/max network. Butterfly merge uses a bitonic lowest-4
// merge (4 shfl + 12 ops). Margin 4e-5 + 2.5e-4*d (eval divergence
// <= ~1.5e-5; d-term covers 13-bit truncation of both d3,d4) — flagged
// points take the exact fp32-rescan + fp64-lexicographic fallback.
// ---------------------------------------------------------------------------
__device__ __forceinline__ uint_t umin_(uint_t a, uint_t b) { return a < b ? a : b; }
__device__ __forceinline__ uint_t umax_(uint_t a, uint_t b) { return a > b ? a : b; }

// insert key into sorted k0<=k1<=k2<=k3, keep 4 smallest (7 min/max ops)
__device__ __forceinline__ void insk(uint_t key,
        uint_t& k0, uint_t& k1, uint_t& k2, uint_t& k3) {
    uint_t t2 = umax_(k2, key);
    uint_t t1 = umax_(k1, key);
    uint_t t0 = umax_(k0, key);
    k3 = umin_(k3, t2);
    k2 = umin_(k2, t1);
    k1 = umin_(k1, t0);
    k0 = umin_(k0, key);
}

// merge partner's sorted quad (via shfl_xor) with mine: bitonic lowest-4.
__device__ __forceinline__ void mrg4(int off,
        uint_t& a0, uint_t& a1, uint_t& a2, uint_t& a3) {
    uint_t e0 = (uint_t)__shfl_xor((int)a0, off);
    uint_t e1 = (uint_t)__shfl_xor((int)a1, off);
    uint_t e2 = (uint_t)__shfl_xor((int)a2, off);
    uint_t e3 = (uint_t)__shfl_xor((int)a3, off);
    uint_t c0 = umin_(a0, e3), c1 = umin_(a1, e2);
    uint_t c2 = umin_(a2, e1), c3 = umin_(a3, e0);   // bitonic, holds 4 smallest
    uint_t l0 = umin_(c0, c2), h0 = umax_(c0, c2);
    uint_t l1 = umin_(c1, c3), h1 = umax_(c1, c3);
    a0 = umin_(l0, l1); a1 = umax_(l0, l1);
    a2 = umin_(h0, h1); a3 = umax_(h0, h1);
}

__device__ __forceinline__ void ins3d(double d, int m,
                                      double& d0, int& i0, double& d1, int& i1,
                                      double& d2, int& i2) {
    if (d < d2 || (d == d2 && m < i2)) {
        d2 = d; i2 = m;
        if (d2 < d1 || (d2 == d1 && i2 < i1)) { double td = d1; d1 = d2; d2 = td; int ti = i1; i1 = i2; i2 = ti; }
        if (d1 < d0 || (d1 == d0 && i1 < i0)) { double td = d0; d0 = d1; d1 = td; int ti = i0; i0 = i1; i1 = ti; }
    }
}

__global__ __launch_bounds__(256) void knn_k(
    const float* __restrict__ unknown, const float* __restrict__ known,
    int4* __restrict__ idx3, float4* __restrict__ wgt3) {
    __shared__ float4 kpt[M_];             // (x, y, z, |k|^2 fp32) — 16 KB
    int b = blockIdx.x >> 7;               // 2048 blocks, 128 per batch
    int n0 = (blockIdx.x & 127) * 32;      // 32 queries per block
    int t = threadIdx.x;
    int qg = t >> 4;                       // query pair 0..15
    int sub = t & 15;                      // candidate slice 0..15

    for (int m = t; m < M_; m += 256) {
        float x = known[((size_t)b * M_ + m) * 3 + 0];
        float y = known[((size_t)b * M_ + m) * 3 + 1];
        float z = known[((size_t)b * M_ + m) * 3 + 2];
        kpt[m] = make_float4(x, y, z, x * x + y * y + z * z);
    }
    __syncthreads();

    int n = n0 + qg * 2;
    float qx0 = unknown[((size_t)b * N_ + n) * 3 + 0];
    float qy0 = unknown[((size_t)b * N_ + n) * 3 + 1];
    float qz0 = unknown[((size_t)b * N_ + n) * 3 + 2];
    float qx1 = unknown[((size_t)b * N_ + n + 1) * 3 + 0];
    float qy1 = unknown[((size_t)b * N_ + n + 1) * 3 + 1];
    float qz1 = unknown[((size_t)b * N_ + n + 1) * 3 + 2];
    float qs0 = qx0 * qx0 + qy0 * qy0 + qz0 * qz0;
    float qs1 = qx1 * qx1 + qy1 * qy1 + qz1 * qz1;

    const uint_t DMASK = 0xFFFFFC00u;
    uint_t A0 = 0xFFFFFFFFu, A1 = 0xFFFFFFFFu, A2 = 0xFFFFFFFFu, A3 = 0xFFFFFFFFu;
    uint_t B0 = 0xFFFFFFFFu, B1 = 0xFFFFFFFFu, B2 = 0xFFFFFFFFu, B3 = 0xFFFFFFFFu;

#pragma unroll 4
    for (int j = 0; j < 64; ++j) {
        int m = j * 16 + sub;
        float4 kp = kpt[m];
        float dot0 = fmaf(qx0, kp.x, fmaf(qy0, kp.y, qz0 * kp.z));
        float d0 = fmaxf(fmaf(-2.0f, dot0, qs0 + kp.w), 0.0f);
        uint_t k0 = (__float_as_uint(d0) & DMASK) | (uint_t)m;
        insk(k0, A0, A1, A2, A3);
        float dot1 = fmaf(qx1, kp.x, fmaf(qy1, kp.y, qz1 * kp.z));
        float d1 = fmaxf(fmaf(-2.0f, dot1, qs1 + kp.w), 0.0f);
        uint_t k1 = (__float_as_uint(d1) & DMASK) | (uint_t)m;
        insk(k1, B0, B1, B2, B3);
    }

    // merge across the 16 subs (lane bits 0..3)
#pragma unroll
    for (int off = 1; off < 16; off <<= 1) {
        mrg4(off, A0, A1, A2, A3);
        mrg4(off, B0, B1, B2, B3);
    }
    // all 16 subs of a query pair now hold the same top-4 keys

#pragma unroll
    for (int qi = 0; qi < 2; ++qi) {
        uint_t K0 = qi ? B0 : A0, K1 = qi ? B1 : A1;
        uint_t K2 = qi ? B2 : A2, K3 = qi ? B3 : A3;
        float qx = qi ? qx1 : qx0, qy = qi ? qy1 : qy0;
        float qz = qi ? qz1 : qz0, qs = qi ? qs1 : qs0;

        float d0t = __uint_as_float(K0 & DMASK);
        float d1t = __uint_as_float(K1 & DMASK);
        float d2t = __uint_as_float(K2 & DMASK);
        float d3t = __uint_as_float(K3 & DMASK);
        float margin = fmaf(d3t, 2.5e-4f, 4.0e-5f);
        bool flagged = (d3t - d2t) <= margin;

        double E0, E1, E2; int F0, F1, F2;
        if (!flagged) {
            E0 = (double)d0t; E1 = (double)d1t; E2 = (double)d2t;
            F0 = (int)(K0 & 0x3FFu);
            F1 = (int)(K1 & 0x3FFu);
            F2 = (int)(K2 & 0x3FFu);
        } else {
            // exact fallback: fp32 rescan + fp64 lexicographic insert for
            // candidates that can possibly be in the true top-3.
            float fthr = d2t + margin;
            double qdx = (double)qx, qdy = (double)qy, qdz = (double)qz;
            double qds = qdx * qdx + qdy * qdy + qdz * qdz;
            double Z0 = 1e300, Z1 = 1e300, Z2 = 1e300;
            int    G0 = 0x7fffffff, G1 = 0x7fffffff, G2 = 0x7fffffff;
            for (int m = sub; m < M_; m += 16) {
                float4 kp = kpt[m];
                float dot = fmaf(qx, kp.x, fmaf(qy, kp.y, qz * kp.z));
                float df = fmaf(-2.0f, dot, qs + kp.w);
                if (df <= fthr) {
                    double X = (double)kp.x, Y = (double)kp.y, Z = (double)kp.z;
                    double ks = X * X + Y * Y + Z * Z;      // same order as fp64 ref
                    double dd = qdx * X + qdy * Y + qdz * Z;
                    double de = qds + ks - 2.0 * dd;
                    ins3d(de, m, Z0, G0, Z1, G1, Z2, G2);
                }
            }
#pragma unroll
            for (int off = 1; off < 16; off <<= 1) {
                double e0 = __shfl_xor(Z0, off), e1 = __shfl_xor(Z1, off), e2 = __shfl_xor(Z2, off);
                int    j0 = __shfl_xor(G0, off), j1 = __shfl_xor(G1, off), j2 = __shfl_xor(G2, off);
                ins3d(e0, j0, Z0, G0, Z1, G1, Z2, G2);
                ins3d(e1, j1, Z0, G0, Z1, G1, Z2, G2);
                ins3d(e2, j2, Z0, G0, Z1, G1, Z2, G2);
            }
            E0 = Z0; E1 = Z1; E2 = Z2;
            F0 = G0; F1 = G1; F2 = G2;
        }

        if (sub == 0) {
            double w0 = 1.0 / (E0 + 1e-8);
            double w1 = 1.0 / (E1 + 1e-8);
            double w2 = 1.0 / (E2 + 1e-8);
            double inv = 1.0 / (w0 + w1 + w2);
            size_t p = (size_t)b * N_ + n + qi;
            idx3[p] = make_int4(F0, F1, F2, 0);
            wgt3[p] = make_float4((float)(w0 * inv), (float)(w1 * inv), (float)(w2 * inv), 0.f);
        }
    }
}

// ---------------------------------------------------------------------------
// Weighted gather: wave per point, 8 points/wave, idx/wgt prefetch depth 1.
// Writes columns 256..767 of A_cat (P, 768) bf16.
// ---------------------------------------------------------------------------
__global__ __launch_bounds__(256) void gather_k(
    const int4* __restrict__ idx3, const float4* __restrict__ wgt3,
    const ushort_t* __restrict__ kfT, ushort_t* __restrict__ Acat) {
    int blk = blockIdx.x;             // 2048 blocks
    int b = blk >> 7;                 // 128 blocks per batch
    int n0 = (blk & 127) * 32;
    int lane = threadIdx.x & 63, wid = threadIdx.x >> 6;

    size_t pbase = (size_t)b * N_ + n0 + wid * 8;
    int4 id = idx3[pbase];
    float4 w = wgt3[pbase];
    for (int it = 0; it < 8; ++it) {
        int4 idn; float4 wn;
        if (it < 7) { idn = idx3[pbase + it + 1]; wn = wgt3[pbase + it + 1]; }
        const uint4* r0 = (const uint4*)(kfT + ((size_t)b * M_ + id.x) * C2_);
        const uint4* r1 = (const uint4*)(kfT + ((size_t)b * M_ + id.y) * C2_);
        const uint4* r2 = (const uint4*)(kfT + ((size_t)b * M_ + id.z) * C2_);
        uint4 v0 = r0[lane], v1 = r1[lane], v2 = r2[lane];
        const ushort_t* p0 = (const ushort_t*)&v0;
        const ushort_t* p1 = (const ushort_t*)&v1;
        const ushort_t* p2 = (const ushort_t*)&v2;
        uint4 o; ushort_t* po = (ushort_t*)&o;
        for (int j = 0; j < 8; ++j) {
            float f = w.x * b2f(p0[j]) + w.y * b2f(p1[j]) + w.z * b2f(p2[j]);
            po[j] = f2b(f);
        }
        ((uint4*)(Acat + (pbase + it) * K1_ + C1_))[lane] = o;
        id = idn; w = wn;
    }
}

// ---------------------------------------------------------------------------
// Unified GEMM: C(P,256) = A(P,K) * Bw(256,K)^T, bf16 MFMA.
// 128x256 tile, 8 waves (512 thr), grid = P/128 = 512 blocks = 2/CU resident.
// 3-buffer pipeline, prefetch depth 2, COUNTED vmcnt + raw s_barrier —
// loads stay in flight across barriers (T3/T4). Per-thread stage = 3
// async16 (1 A + 2 B) -> steady-state vmcnt(6), tail vmcnt(3)/vmcnt(0).
// Staging is the ONLY VMEM in the loop, so the counts are exact.
// XOR swizzle on both sides (verified conflict-free).
// ---------------------------------------------------------------------------
__global__ __launch_bounds__(512, 4) void gemm_k(
    const ushort_t* __restrict__ A, const ushort_t* __restrict__ Bw,
    ushort_t* __restrict__ C, int K) {
    __shared__ ushort_t As[3][128 * 32];
    __shared__ ushort_t Bs[3][256 * 32];
    int t = threadIdx.x, lane = t & 63, wid = t >> 6;
    int wm = wid & 1, wn = wid >> 1;           // 2 x 4 wave grid -> 64x64 each
    int row0 = blockIdx.x * 128;
    int quad = lane >> 4, l15 = lane & 15;
    int srow = lane >> 2, kc = lane & 3;
    int kcs = kc ^ ((srow >> 1) & 3);          // swizzled source chunk
    int rsw = (l15 >> 1) & 3;                  // read-side swizzle key

    f32x4 acc[4][4] = {};

    auto stage = [&](int buf, int k0) {
        async16(A + ((size_t)(row0 + wid * 16 + srow)) * K + k0 + kcs * 8,
                &As[buf][wid * 16 * 32]);
#pragma unroll
        for (int j = 0; j < 2; ++j) {
            int rbase = wid * 32 + j * 16;
            async16(Bw + ((size_t)(rbase + srow)) * K + k0 + kcs * 8,
                    &Bs[buf][rbase * 32]);
        }
    };

    int nt = K >> 5;                 // 24 or 8
    stage(0, 0);
    stage(1, 32);

    int bi = 0;
    for (int it = 0; it < nt; ++it) {
        int pf = it + 2;
        if (pf < nt) stage(pf % 3, pf * 32);

        if (it < nt - 2)      asm volatile("s_waitcnt vmcnt(6)" ::: "memory");
        else if (it == nt - 2) asm volatile("s_waitcnt vmcnt(3)" ::: "memory");
        else                  asm volatile("s_waitcnt vmcnt(0)" ::: "memory");
        __builtin_amdgcn_s_barrier();          // all waves' tile-it loads landed
        asm volatile("" ::: "memory");

        s16x8 af[4], bfr[4];
#pragma unroll
        for (int i = 0; i < 4; ++i)
            af[i] = *(const s16x8*)&As[bi][(wm * 64 + i * 16 + l15) * 32 + ((quad ^ rsw) * 8)];
#pragma unroll
        for (int j = 0; j < 4; ++j)
            bfr[j] = *(const s16x8*)&Bs[bi][(wn * 64 + j * 16 + l15) * 32 + ((quad ^ rsw) * 8)];
#pragma unroll
        for (int i = 0; i < 4; ++i)
#pragma unroll
            for (int j = 0; j < 4; ++j)
                acc[i][j] = __builtin_amdgcn_mfma_f32_16x16x32_bf16(
                    af[i], bfr[j], acc[i][j], 0, 0, 0);

        asm volatile("" ::: "memory");
        __builtin_amdgcn_s_barrier();          // reads of buf bi done -> reusable
        asm volatile("" ::: "memory");
        bi = (bi + 1 == 3) ? 0 : bi + 1;
    }

    for (int i = 0; i < 4; ++i)
        for (int j = 0; j < 4; ++j)
            for (int r = 0; r < 4; ++r) {
                int m = row0 + wm * 64 + i * 16 + quad * 4 + r;
                int n = wn * 64 + j * 16 + l15;
                C[(size_t)m * H_ + n] = f2b(acc[i][j][r]);
            }
}

// ---------------------------------------------------------------------------
__global__ __launch_bounds__(256) void stats_k(
    const ushort_t* __restrict__ x, float* __restrict__ sum, float* __restrict__ sq) {
    int t = threadIdx.x;
    int r0 = blockIdx.x * 256;
    float s = 0.f, q = 0.f;
    for (int r = 0; r < 256; ++r) {
        float v = b2f(x[(size_t)(r0 + r) * 256 + t]);
        s += v; q += v * v;
    }
    atomicAdd(&sum[t], s);
    atomicAdd(&sq[t], q);
}

__global__ __launch_bounds__(256) void coef_k(
    const float* __restrict__ sum, const float* __restrict__ sq,
    const float* __restrict__ g, const float* __restrict__ bt,
    float* __restrict__ a, float* __restrict__ c) {
    int t = threadIdx.x;
    float mean = sum[t] * (1.0f / P_);
    float var  = sq[t] * (1.0f / P_) - mean * mean;
    float ai = g[t] * rsqrtf(var + 1e-5f);
    a[t] = ai;
    c[t] = bt[t] - mean * ai;
}

// BN + ReLU elementwise: x1 (P,256) bf16 -> h1 bf16, one uint4 (8 elems)/thread
__global__ __launch_bounds__(256) void bnrelu_k(
    const uint4* __restrict__ x, const float* __restrict__ a,
    const float* __restrict__ c, uint4* __restrict__ h) {
    size_t i = (size_t)blockIdx.x * 256 + threadIdx.x;   // 2,097,152 uint4s
    uint4 v = x[i];
    int chb = (int)((i * 8) & 255);
    const ushort_t* pv = (const ushort_t*)&v;
    uint4 o; ushort_t* po = (ushort_t*)&o;
    for (int j = 0; j < 8; ++j) {
        float f = b2f(pv[j]);
        f = a[chb + j] * f + c[chb + j];
        po[j] = f2b(fmaxf(f, 0.0f));
    }
    h[i] = o;
}

// BN + ReLU + transpose: x2 (P,256) bf16 -> out (B,256,N) f32, 64x64 tiles
__global__ __launch_bounds__(256) void final_k(
    const ushort_t* __restrict__ x2, const float* __restrict__ a,
    const float* __restrict__ c, float* __restrict__ out) {
    __shared__ float tile[64][65];
    int n0 = blockIdx.x * 64, c0 = blockIdx.y * 64, b = blockIdx.z;
    int t = threadIdx.x;
    {
        int cl = t & 63, pb = (t >> 6) * 16;
        float av = a[c0 + cl], cv = c[c0 + cl];
        for (int i = 0; i < 16; ++i) {
            float v = b2f(x2[((size_t)b * N_ + n0 + pb + i) * H_ + c0 + cl]);
            tile[cl][pb + i] = fmaxf(av * v + cv, 0.0f);
        }
    }
    __syncthreads();
    {
        int nl = t & 63, cb = (t >> 6) * 16;
        for (int i = 0; i < 16; ++i)
            out[((size_t)b * H_ + c0 + cb + i) * N_ + n0 + nl] = tile[cb + i][nl];
    }
}

// ---------------------------------------------------------------------------
extern "C" void kernel_launch(void* const* d_in, const int* in_sizes, int n_in,
                              void* d_out, int out_size, void* d_ws, size_t ws_size,
                              hipStream_t stream) {
    const float* unknown = (const float*)d_in[0];
    const float* known   = (const float*)d_in[1];
    const float* uf      = (const float*)d_in[2];
    const float* kf      = (const float*)d_in[3];
    const float* w1      = (const float*)d_in[4];
    const float* g1      = (const float*)d_in[5];
    const float* b1      = (const float*)d_in[6];
    const float* w2      = (const float*)d_in[7];
    const float* g2      = (const float*)d_in[8];
    const float* b2      = (const float*)d_in[9];
    float* out = (float*)d_out;

    char* ws = (char*)d_ws;
    // [0, 8K): stats — sum1,sq1,sum2,sq2,a1,c1,a2,c2 (8 x 256 f32)
    float* sum1 = (float*)ws;
    float* sq1  = sum1 + 256;
    float* sum2 = sum1 + 512;
    float* sq2  = sum1 + 768;
    float* a1   = sum1 + 1024;
    float* c1   = sum1 + 1280;
    float* a2   = sum1 + 1536;
    float* c2   = sum1 + 1792;
    // [8K, ~520K): converted weights
    ushort_t* w1b = (ushort_t*)(ws + 8192);                        // 384 KB
    ushort_t* w2b = (ushort_t*)(ws + 8192 + (size_t)H_ * K1_ * 2); // 128 KB
    const size_t MB = 1024 * 1024;
    // Lifetimes (stream-serialized):
    //   Acat [1,97): tuf_k (cols 0..255) + gather_k (256..767) -> gemm1.
    //   kfT  [97,113): tkf_k -> gather_k.
    //   idx3/wgt3 [113,115): knn -> gather.
    //   x1   [97,129): gemm1 (kfT/idx3/wgt3 dead by then).
    //   h1   [1,33):  bnrelu (Acat dead) -> gemm2.
    //   x2   [33,65): gemm2 -> stats2/final.
    // Peak 129 MB.
    ushort_t* Acat = (ushort_t*)(ws + 1 * MB);      // 96 MB
    ushort_t* kfT  = (ushort_t*)(ws + 97 * MB);     // 16 MB
    int4*   idx3 = (int4*)(ws + 113 * MB);          // 1 MB
    float4* wgt3 = (float4*)(ws + 114 * MB);        // 1 MB
    ushort_t* x1   = (ushort_t*)(ws + 97 * MB);     // 32 MB
    ushort_t* h1   = (ushort_t*)(ws + 1 * MB);      // 32 MB
    ushort_t* x2   = (ushort_t*)(ws + 33 * MB);     // 32 MB

    zero_k<<<8, 256, 0, stream>>>(sum1);
    cvtw_k<<<1024, 256, 0, stream>>>(w1, w2, w1b, w2b);
    tkf_k<<<dim3(16, 8, 16), 256, 0, stream>>>(kf, kfT);
    tuf_k<<<dim3(64, 4, 16), 256, 0, stream>>>(uf, Acat);
    knn_k<<<2048, 256, 0, stream>>>(unknown, known, idx3, wgt3);
    gather_k<<<2048, 256, 0, stream>>>(idx3, wgt3, kfT, Acat);
    gemm_k<<<512, 512, 0, stream>>>(Acat, w1b, x1, K1_);
    stats_k<<<256, 256, 0, stream>>>(x1, sum1, sq1);
    coef_k<<<1, 256, 0, stream>>>(sum1, sq1, g1, b1, a1, c1);
    bnrelu_k<<<8192, 256, 0, stream>>>((const uint4*)x1, a1, c1, (uint4*)h1);
    gemm_k<<<512, 512, 0, stream>>>(h1, w2b, x2, H_);
    stats_k<<<256, 256, 0, stream>>>(x2, sum2, sq2);
    coef_k<<<1, 256, 0, stream>>>(sum2, sq2, g2, b2, a2, c2);
    final_k<<<dim3(64, 4, 16), 256, 0, stream>>>(x2, a2, c2, out);
}